// Round 3
// baseline (509.696 us; speedup 1.0000x reference)
//
#include <hip/hip_runtime.h>

// ---- types ------------------------------------------------------------
typedef short short8 __attribute__((ext_vector_type(8)));   // 8 bf16 (4 VGPR) MFMA A/B frag
typedef float f32x4  __attribute__((ext_vector_type(4)));   // MFMA C/D frag
typedef unsigned int u32x4 __attribute__((ext_vector_type(4))); // 16B load vehicle

union V16  { u32x4 v; short8 s; };
union U16x8 { u32x4 v; unsigned short u[8]; };
union FB4  { u32x4 v; float f[4]; };

__device__ inline unsigned short f2bf(float f) {
  union { float f; unsigned int u; } x; x.f = f;
  unsigned int u = x.u + 0x7fffu + ((x.u >> 16) & 1u);   // RNE
  return (unsigned short)(u >> 16);
}

// ---- dtype probe -------------------------------------------------------
// Even-indexed u16 words of a bf16 N(0,1) tensor have exponent ~[117,129].
// For an fp32 tensor those words are mantissa-low bits: ~38% land outside.
__global__ void probe_dtype(const unsigned short* __restrict__ hs, int* __restrict__ flag) {
  if (threadIdx.x == 0) {
    int bad = 0;
    for (int i = 0; i < 64; ++i) {
      unsigned int e = (hs[2 * i] >> 7) & 0xFFu;
      if (e >= 0xFEu || (e > 0u && e < 0x60u)) bad++;
    }
    *flag = (bad >= 6) ? 1 : 0;   // 1 => inputs are fp32
  }
}

// ---- transpose (+ optional fp32->bf16 convert): out[C][R] = bf16(in[R][C])
__global__ __launch_bounds__(256) void tr_any(const void* __restrict__ in_,
                                              unsigned short* __restrict__ out,
                                              int R, int C, const int* flagp) {
  __shared__ unsigned short t[32][33];
  const int f = flagp ? *flagp : 0;
  const size_t base = (size_t)blockIdx.z * R * C;
  const int tx = threadIdx.x & 31, ty = threadIdx.x >> 5;
  const int r0 = blockIdx.y * 32, c0 = blockIdx.x * 32;
#pragma unroll
  for (int i = 0; i < 4; ++i) {
    size_t idx = base + (size_t)(r0 + ty + 8 * i) * C + (c0 + tx);
    unsigned short w = f ? f2bf(((const float*)in_)[idx])
                         : ((const unsigned short*)in_)[idx];
    t[ty + 8 * i][tx] = w;
  }
  __syncthreads();
#pragma unroll
  for (int i = 0; i < 4; ++i)
    out[base + (size_t)(c0 + ty + 8 * i) * R + (r0 + tx)] = t[tx][ty + 8 * i];
}

// ---- C[M][N] = A[M][K] @ BT[N][K]^T -----------------------------------
// A is bf16 (aflagp null/0) or fp32 (flag 1); BT always bf16 (internal).
// C store is bf16 unless *oflagp==1 (then fp32).
// 128x128 tile, BK=32, 4 waves in 2x2 quadrants of 64x64.
__global__ __launch_bounds__(256) void gemm_bt(const void* __restrict__ A_,
                                               const unsigned short* __restrict__ BT,
                                               void* __restrict__ C_,
                                               int M, int N, int K,
                                               const int* aflagp, const int* oflagp) {
  __shared__ unsigned short As[128][40];  // +8 pad
  __shared__ unsigned short Bs[128][40];
  const int af = aflagp ? *aflagp : 0;
  const int of = oflagp ? *oflagp : 0;
  const int m0 = blockIdx.y * 128, n0 = blockIdx.x * 128;
  const int tid = threadIdx.x;
  const int lane = tid & 63, w = tid >> 6;
  const int wr = w >> 1, wc = w & 1;
  const int quad = lane >> 4, mrow = lane & 15;

  const f32x4 zf = {0.f, 0.f, 0.f, 0.f};
  f32x4 acc[4][4];
#pragma unroll
  for (int mt = 0; mt < 4; ++mt)
#pragma unroll
    for (int nt = 0; nt < 4; ++nt) acc[mt][nt] = zf;

  for (int k0 = 0; k0 < K; k0 += 32) {
    __syncthreads();
#pragma unroll
    for (int i = 0; i < 2; ++i) {
      int slot = tid + i * 256;           // 512 slots x 8 elements
      int row = slot >> 2;
      int kc = (slot & 3) << 3;
      size_t off = (size_t)(m0 + row) * K + k0 + kc;
      if (af) {                           // fp32 A: 2x16B load, convert to 8 bf16
        const float* Af = (const float*)A_;
        FB4 w0, w1; w0.v = *(const u32x4*)&Af[off]; w1.v = *(const u32x4*)&Af[off + 4];
        U16x8 p;
#pragma unroll
        for (int j = 0; j < 4; ++j) { p.u[j] = f2bf(w0.f[j]); p.u[j + 4] = f2bf(w1.f[j]); }
        *(u32x4*)&As[row][kc] = p.v;
      } else {
        *(u32x4*)&As[row][kc] = *(const u32x4*)((const unsigned short*)A_ + off);
      }
      *(u32x4*)&Bs[row][kc] = *(const u32x4*)&BT[(size_t)(n0 + row) * K + k0 + kc];
    }
    __syncthreads();
    short8 afr[4], bfr[4];
#pragma unroll
    for (int mt = 0; mt < 4; ++mt) {
      V16 u; u.v = *(const u32x4*)&As[wr * 64 + mt * 16 + mrow][quad * 8];
      afr[mt] = u.s;
    }
#pragma unroll
    for (int nt = 0; nt < 4; ++nt) {
      V16 u; u.v = *(const u32x4*)&Bs[wc * 64 + nt * 16 + mrow][quad * 8];
      bfr[nt] = u.s;
    }
#pragma unroll
    for (int mt = 0; mt < 4; ++mt)
#pragma unroll
      for (int nt = 0; nt < 4; ++nt)
        acc[mt][nt] = __builtin_amdgcn_mfma_f32_16x16x32_bf16(afr[mt], bfr[nt], acc[mt][nt], 0, 0, 0);
  }
#pragma unroll
  for (int mt = 0; mt < 4; ++mt)
#pragma unroll
    for (int nt = 0; nt < 4; ++nt)
#pragma unroll
      for (int r = 0; r < 4; ++r) {
        int grow = m0 + wr * 64 + mt * 16 + quad * 4 + r;   // C/D row = quad*4+reg
        int gcol = n0 + wc * 64 + nt * 16 + mrow;           // C/D col = lane&15
        size_t idx = (size_t)grow * N + gcol;
        if (of) ((float*)C_)[idx] = acc[mt][nt][r];
        else    ((unsigned short*)C_)[idx] = f2bf(acc[mt][nt][r]);
      }
}

// ---- fused causal "based" attention (all-internal bf16 buffers) -------
// qk: [B*L][384] (cols 0..191 = q, 192..383 = k); vT: [B*H*128][2048]; obuf: [B*L][1536]
// grid (24, 32): (b*12+h, 64-row q tile). 4 waves x 16 q-rows each.
__global__ __launch_bounds__(256) void attn_based(const unsigned short* __restrict__ qk,
                                                  const unsigned short* __restrict__ vT,
                                                  unsigned short* __restrict__ obuf) {
  __shared__ unsigned short plds[4][16][72];  // per-wave P tile, +8 pad
  const int bh = blockIdx.x;
  const int qt = blockIdx.y;
  const int b = bh / 12, h = bh % 12;
  const int lane = threadIdx.x & 63, w = threadIdx.x >> 6;
  const int quad = lane >> 4, mrow = lane & 15;
  const f32x4 zf = {0.f, 0.f, 0.f, 0.f};

  // q A-frag: A[m=lane&15][k=quad*8+j]; feature dim 16 -> quads 2,3 zero
  short8 aq = {0, 0, 0, 0, 0, 0, 0, 0};
  const int qrow = qt * 64 + w * 16 + mrow;
  if (quad < 2) {
    V16 u; u.v = *(const u32x4*)&qk[(size_t)(b * 2048 + qrow) * 384 + h * 16 + quad * 8];
    aq = u.s;
  }

  f32x4 oacc[8];
#pragma unroll
  for (int nt = 0; nt < 8; ++nt) oacc[nt] = zf;
  float zacc[4] = {0.f, 0.f, 0.f, 0.f};

  const int rowb = qt * 64 + w * 16 + quad * 4;  // C-layout base row

  for (int kt = 0; kt <= qt; ++kt) {   // uniform trip count across the block
    const int kv0 = kt * 64;
    f32x4 sacc[4];
#pragma unroll
    for (int jt = 0; jt < 4; ++jt) {
      short8 bk = {0, 0, 0, 0, 0, 0, 0, 0};
      if (quad < 2) {
        int kvr = kv0 + jt * 16 + mrow;
        V16 u; u.v = *(const u32x4*)&qk[(size_t)(b * 2048 + kvr) * 384 + 192 + h * 16 + quad * 8];
        bk = u.s;
      }
      sacc[jt] = __builtin_amdgcn_mfma_f32_16x16x32_bf16(aq, bk, zf, 0, 0, 0);
    }
    __syncthreads();   // prior iteration's P reads complete before overwrite
    // attn = 1 + 0.25*s_raw + 0.03125*s_raw^2  (folds q * FDIM^-0.5 exactly)
#pragma unroll
    for (int jt = 0; jt < 4; ++jt) {
      const int col = kv0 + jt * 16 + mrow;
#pragma unroll
      for (int r = 0; r < 4; ++r) {
        float s = sacc[jt][r];
        float a = 1.0f + 0.25f * s + 0.03125f * s * s;
        a = (col <= rowb + r) ? a : 0.0f;
        zacc[r] += a;
        plds[w][quad * 4 + r][jt * 16 + mrow] = f2bf(a);
      }
    }
    __syncthreads();   // P stores visible (and compiler-ordered) before reads
    // P (A-layout) @ v
#pragma unroll
    for (int c = 0; c < 2; ++c) {
      union { short8 s; unsigned short u[8]; } apu;
#pragma unroll
      for (int j = 0; j < 8; ++j)
        apu.u[j] = plds[w][mrow][c * 32 + quad * 8 + j];
      short8 ap = apu.s;
#pragma unroll
      for (int nt = 0; nt < 8; ++nt) {
        V16 u;
        u.v = *(const u32x4*)&vT[(size_t)(bh * 128 + nt * 16 + mrow) * 2048 +
                                 kv0 + c * 32 + quad * 8];
        oacc[nt] = __builtin_amdgcn_mfma_f32_16x16x32_bf16(ap, u.s, oacc[nt], 0, 0, 0);
      }
    }
  }
  float inv[4];
#pragma unroll
  for (int r = 0; r < 4; ++r) {
    float z = zacc[r];
    z += __shfl_xor(z, 1);
    z += __shfl_xor(z, 2);
    z += __shfl_xor(z, 4);
    z += __shfl_xor(z, 8);
    inv[r] = 1.0f / (z + 1e-12f);
  }
#pragma unroll
  for (int nt = 0; nt < 8; ++nt)
#pragma unroll
    for (int r = 0; r < 4; ++r)
      obuf[(size_t)(b * 2048 + rowb + r) * 1536 + h * 128 + nt * 16 + mrow] =
          f2bf(oacc[nt][r] * inv[r]);
}

// ---- launch -----------------------------------------------------------
extern "C" void kernel_launch(void* const* d_in, const int* in_sizes, int n_in,
                              void* d_out, int out_size, void* d_ws, size_t ws_size,
                              hipStream_t stream) {
  const void* hs = d_in[0];
  const void* Wq = d_in[1];
  const void* Wk = d_in[2];
  const void* Wv = d_in[3];
  const void* Wo = d_in[4];

  // ws layout (~34.2 MB):
  //   [flag int][pad to 128 el]
  //   WqkT [384][1536] | WB [1536][1536] | qkb [4096][384] | vbuf [4096][1536] | vT [2*1536][2048]
  int* flag = (int*)d_ws;
  unsigned short* ws   = (unsigned short*)d_ws + 128;
  unsigned short* WqkT = ws;
  unsigned short* WB   = WqkT + 384 * 1536;
  unsigned short* qkb  = WB + 1536 * 1536;
  unsigned short* vbuf = qkb + 4096 * 384;
  unsigned short* vT   = vbuf + 4096 * 1536;
  unsigned short* obuf = vbuf;                 // vbuf dead after v transpose

  probe_dtype<<<1, 64, 0, stream>>>((const unsigned short*)d_in[0], flag);

  // weights -> bf16 B^T layout (convert-on-load per flag)
  tr_any<<<dim3(6, 48, 1), 256, 0, stream>>>(Wq, WqkT, 1536, 192, flag);
  tr_any<<<dim3(6, 48, 1), 256, 0, stream>>>(Wk, WqkT + 192 * 1536, 1536, 192, flag);
  tr_any<<<dim3(48, 48, 1), 256, 0, stream>>>(Wv, WB, 1536, 1536, flag);

  // projections (A = hs, dtype per flag; outputs internal bf16)
  gemm_bt<<<dim3(3, 32, 1), 256, 0, stream>>>(hs, WqkT, qkb, 4096, 384, 1536, flag, nullptr);
  gemm_bt<<<dim3(12, 32, 1), 256, 0, stream>>>(hs, WB, vbuf, 4096, 1536, 1536, flag, nullptr);

  // v -> per-(b,h) [hd][l] (internal bf16 input: flagp=null)
  tr_any<<<dim3(48, 64, 2), 256, 0, stream>>>(vbuf, vT, 2048, 1536, nullptr);

  // Wo -> B^T (reuses WB after the v gemm)
  tr_any<<<dim3(48, 48, 1), 256, 0, stream>>>(Wo, WB, 1536, 1536, flag);

  // fused causal based-attention
  attn_based<<<dim3(24, 32, 1), 256, 0, stream>>>(qkb, vT, obuf);

  // output projection -> d_out (store dtype per flag)
  gemm_bt<<<dim3(12, 32, 1), 256, 0, stream>>>(obuf, WB, d_out, 4096, 1536, 1536, nullptr, flag);
}

// Round 5
// 393.946 us; speedup vs baseline: 1.2938x; 1.2938x over previous
//
#include <hip/hip_runtime.h>

// ---- types ------------------------------------------------------------
typedef short short8 __attribute__((ext_vector_type(8)));   // 8 bf16 MFMA A/B frag
typedef float f32x4  __attribute__((ext_vector_type(4)));   // MFMA C/D frag
typedef unsigned int u32x4 __attribute__((ext_vector_type(4))); // 16B vehicle

union V16   { u32x4 v; short8 s; };
union U16x8 { u32x4 v; unsigned short u[8]; };
union FB4   { u32x4 v; float f[4]; };

__device__ inline unsigned short f2bf(float f) {
  union { float f; unsigned int u; } x; x.f = f;
  unsigned int u = x.u + 0x7fffu + ((x.u >> 16) & 1u);   // RNE
  return (unsigned short)(u >> 16);
}

// ---- dtype probe (fp32 vs bf16 inputs) --------------------------------
__global__ void probe_dtype(const unsigned short* __restrict__ hs, int* __restrict__ flag) {
  if (threadIdx.x == 0) {
    int bad = 0;
    for (int i = 0; i < 64; ++i) {
      unsigned int e = (hs[2 * i] >> 7) & 0xFFu;
      if (e >= 0xFEu || (e > 0u && e < 0x60u)) bad++;
    }
    *flag = (bad >= 6) ? 1 : 0;   // 1 => fp32
  }
}

// ---- hs -> bf16 contiguous (one-time convert; 8 el/thread) ------------
__global__ __launch_bounds__(256) void cvt_hs(const void* __restrict__ in_,
                                              unsigned short* __restrict__ out,
                                              const int* flagp) {
  const int f = *flagp;
  size_t i0 = ((size_t)blockIdx.x * 256 + threadIdx.x) * 8;
  if (f) {
    const float* in = (const float*)in_;
    FB4 a, b; a.v = *(const u32x4*)&in[i0]; b.v = *(const u32x4*)&in[i0 + 4];
    U16x8 p;
#pragma unroll
    for (int j = 0; j < 4; ++j) { p.u[j] = f2bf(a.f[j]); p.u[j + 4] = f2bf(b.f[j]); }
    *(u32x4*)&out[i0] = p.v;
  } else {
    *(u32x4*)&out[i0] = *(const u32x4*)((const unsigned short*)in_ + i0);
  }
}

// ---- transpose (+optional fp32->bf16): out[z][c][r] = bf16(in[z][r][c]) ----
__global__ __launch_bounds__(256) void tr_any(const void* __restrict__ in_,
                                              unsigned short* __restrict__ out,
                                              int R, int C, int ldin,
                                              long long in_bstride, long long out_bstride,
                                              const int* flagp) {
  __shared__ unsigned short t[32][33];
  const int f = flagp ? *flagp : 0;
  const size_t ibase = (size_t)blockIdx.z * in_bstride;
  const size_t obase = (size_t)blockIdx.z * out_bstride;
  const int tx = threadIdx.x & 31, ty = threadIdx.x >> 5;
  const int r0 = blockIdx.y * 32, c0 = blockIdx.x * 32;
#pragma unroll
  for (int i = 0; i < 4; ++i) {
    size_t idx = ibase + (size_t)(r0 + ty + 8 * i) * ldin + (c0 + tx);
    t[ty + 8 * i][tx] = f ? f2bf(((const float*)in_)[idx])
                          : ((const unsigned short*)in_)[idx];
  }
  __syncthreads();
#pragma unroll
  for (int i = 0; i < 4; ++i)
    out[obase + (size_t)(c0 + ty + 8 * i) * R + (r0 + tx)] = t[tx][ty + 8 * i];
}

// ---- C[M][N] = A[M][K] @ BT[N][K]^T, A/BT bf16; C bf16 or fp32 (oflag) ----
// 128x128 tile, BK=32, 4 waves in 2x2 quadrants of 64x64.
__global__ __launch_bounds__(256) void gemm_bt(const unsigned short* __restrict__ A,
                                               const unsigned short* __restrict__ BT,
                                               void* __restrict__ C_,
                                               int M, int N, int K,
                                               const int* oflagp) {
  __shared__ unsigned short As[128][40];  // +8 pad
  __shared__ unsigned short Bs[128][40];
  const int of = oflagp ? *oflagp : 0;
  const int m0 = blockIdx.y * 128, n0 = blockIdx.x * 128;
  const int tid = threadIdx.x;
  const int lane = tid & 63, w = tid >> 6;
  const int wr = w >> 1, wc = w & 1;
  const int quad = lane >> 4, mrow = lane & 15;

  const f32x4 zf = {0.f, 0.f, 0.f, 0.f};
  f32x4 acc[4][4];
#pragma unroll
  for (int mt = 0; mt < 4; ++mt)
#pragma unroll
    for (int nt = 0; nt < 4; ++nt) acc[mt][nt] = zf;

  for (int k0 = 0; k0 < K; k0 += 32) {
    __syncthreads();
#pragma unroll
    for (int i = 0; i < 2; ++i) {
      int slot = tid + i * 256;
      int row = slot >> 2;
      int kc = (slot & 3) << 3;
      *(u32x4*)&As[row][kc] = *(const u32x4*)&A [(size_t)(m0 + row) * K + k0 + kc];
      *(u32x4*)&Bs[row][kc] = *(const u32x4*)&BT[(size_t)(n0 + row) * K + k0 + kc];
    }
    __syncthreads();
    short8 afr[4], bfr[4];
#pragma unroll
    for (int mt = 0; mt < 4; ++mt) {
      V16 u; u.v = *(const u32x4*)&As[wr * 64 + mt * 16 + mrow][quad * 8];
      afr[mt] = u.s;
    }
#pragma unroll
    for (int nt = 0; nt < 4; ++nt) {
      V16 u; u.v = *(const u32x4*)&Bs[wc * 64 + nt * 16 + mrow][quad * 8];
      bfr[nt] = u.s;
    }
#pragma unroll
    for (int mt = 0; mt < 4; ++mt)
#pragma unroll
      for (int nt = 0; nt < 4; ++nt)
        acc[mt][nt] = __builtin_amdgcn_mfma_f32_16x16x32_bf16(afr[mt], bfr[nt], acc[mt][nt], 0, 0, 0);
  }
#pragma unroll
  for (int mt = 0; mt < 4; ++mt)
#pragma unroll
    for (int nt = 0; nt < 4; ++nt)
#pragma unroll
      for (int r = 0; r < 4; ++r) {
        int grow = m0 + wr * 64 + mt * 16 + quad * 4 + r;
        int gcol = n0 + wc * 64 + nt * 16 + mrow;
        size_t idx = (size_t)grow * N + gcol;
        if (of) ((float*)C_)[idx] = acc[mt][nt][r];
        else    ((unsigned short*)C_)[idx] = f2bf(acc[mt][nt][r]);
      }
}

// ---- fused causal "based" attention — barrier-free K-loop -------------
// qkv: [4096][1920] bf16 (cols 0..191 q, 192..383 k); vT: [24*128][2048]
// obuf: [4096][1536]. grid (24,32): (b*12+h, q-tile). 4 waves x 16 q-rows.
// S^T via MFMA; P moved to PV A-operand layout with 16 shfls/iteration:
//   dest (quad,mrow) word t needs pk[2c + (quad>>1)][t&1] from lane
//   (2*(quad&1)+(t>>1))*16+mrow  -> shuffle BOTH jt candidates, select on dest
//   (one shfl can't serve quads 0 and 2: same source lane, different jt).
__global__ __launch_bounds__(256) void attn_based(const unsigned short* __restrict__ qkv,
                                                  const unsigned short* __restrict__ vT,
                                                  unsigned short* __restrict__ obuf) {
  const int LD = 1920;
  const int bh = blockIdx.x;
  const int qt = 31 - blockIdx.y;         // long blocks dispatch first
  const int b = bh / 12, h = bh % 12;
  const int lane = threadIdx.x & 63, w = threadIdx.x >> 6;
  const int quad = lane >> 4, mrow = lane & 15;
  const f32x4 zf = {0.f, 0.f, 0.f, 0.f};

  // q B-frag (loop-invariant): B[n=q=mrow][k=feature=quad*8+j]; quads 2,3 zero
  short8 bq = {0, 0, 0, 0, 0, 0, 0, 0};
  const int q_abs = qt * 64 + w * 16 + mrow;
  if (quad < 2) {
    V16 u; u.v = *(const u32x4*)&qkv[(size_t)(b * 2048 + q_abs) * LD + h * 16 + quad * 8];
    bq = u.s;
  }

  f32x4 oacc[8];
#pragma unroll
  for (int nt = 0; nt < 8; ++nt) oacc[nt] = zf;
  float zcol = 0.f;                        // partial z for column q = mrow

  for (int kt = 0; kt <= qt; ++kt) {
    const int kv0 = kt * 64;
    // S^T tiles: A-frag from k rows (m=kv), B-frag = bq (n=q)
    unsigned int pk[4][2];                 // bf16-packed P pairs per tile
#pragma unroll
    for (int jt = 0; jt < 4; ++jt) {
      short8 ak = {0, 0, 0, 0, 0, 0, 0, 0};
      if (quad < 2) {
        int kvr = kv0 + jt * 16 + mrow;
        V16 u; u.v = *(const u32x4*)&qkv[(size_t)(b * 2048 + kvr) * LD + 192 + h * 16 + quad * 8];
        ak = u.s;
      }
      f32x4 st = __builtin_amdgcn_mfma_f32_16x16x32_bf16(ak, bq, zf, 0, 0, 0);
      // st: row = kv_in_tile = quad*4+r, col = q = mrow
      const int kvb = kv0 + jt * 16 + quad * 4;
#pragma unroll
      for (int r2 = 0; r2 < 2; ++r2) {
        float s0 = st[2 * r2], s1 = st[2 * r2 + 1];
        float a0 = fmaf(s0, fmaf(s0, 0.03125f, 0.25f), 1.0f);  // 1+0.25s+0.03125s^2
        float a1 = fmaf(s1, fmaf(s1, 0.03125f, 0.25f), 1.0f);  // (folds FDIM^-0.5)
        a0 = (kvb + 2 * r2     <= q_abs) ? a0 : 0.0f;
        a1 = (kvb + 2 * r2 + 1 <= q_abs) ? a1 : 0.0f;
        zcol += a0 + a1;
        pk[jt][r2] = (unsigned int)f2bf(a0) | ((unsigned int)f2bf(a1) << 16);
      }
    }
    // wave transpose C/D -> A layout + PV MFMAs
#pragma unroll
    for (int c = 0; c < 2; ++c) {
      union { short8 s; int wd[4]; } ap;
#pragma unroll
      for (int t = 0; t < 4; ++t) {
        int src = (2 * (quad & 1) + (t >> 1)) * 16 + mrow;
        int v0 = __shfl((int)pk[2 * c][t & 1], src, 64);
        int v1 = __shfl((int)pk[2 * c + 1][t & 1], src, 64);
        ap.wd[t] = (quad >> 1) ? v1 : v0;
      }
#pragma unroll
      for (int nt = 0; nt < 8; ++nt) {
        V16 u;
        u.v = *(const u32x4*)&vT[(size_t)(bh * 128 + nt * 16 + mrow) * 2048 +
                                 kv0 + c * 32 + quad * 8];
        oacc[nt] = __builtin_amdgcn_mfma_f32_16x16x32_bf16(ap.s, u.s, oacc[nt], 0, 0, 0);
      }
    }
  }
  // z: reduce partial column sums across quads; broadcast to O rows
  zcol += __shfl_xor(zcol, 16, 64);
  zcol += __shfl_xor(zcol, 32, 64);
  float inv[4];
#pragma unroll
  for (int r = 0; r < 4; ++r)
    inv[r] = 1.0f / (__shfl(zcol, quad * 4 + r, 64) + 1e-12f);
#pragma unroll
  for (int nt = 0; nt < 8; ++nt)
#pragma unroll
    for (int r = 0; r < 4; ++r)
      obuf[(size_t)(b * 2048 + qt * 64 + w * 16 + quad * 4 + r) * 1536 +
           h * 128 + nt * 16 + mrow] = f2bf(oacc[nt][r] * inv[r]);
}

// ---- launch -----------------------------------------------------------
extern "C" void kernel_launch(void* const* d_in, const int* in_sizes, int n_in,
                              void* d_out, int out_size, void* d_ws, size_t ws_size,
                              hipStream_t stream) {
  const void* hs = d_in[0];
  const void* Wq = d_in[1];
  const void* Wk = d_in[2];
  const void* Wv = d_in[3];
  const void* Wo = d_in[4];

  // ws (~46.8 MB): flag | WT[1920][1536] | qkvb[4096][1920] | hsb[4096][1536] | vT[24*128][2048]
  int* flag = (int*)d_ws;
  unsigned short* ws   = (unsigned short*)d_ws + 128;
  unsigned short* WT   = ws;                        // q rows 0..191, k 192..383, v 384..1919
  unsigned short* qkvb = WT + 1920 * 1536;
  unsigned short* hsb  = qkvb + 4096 * 1920;
  unsigned short* vT   = hsb + 4096 * 1536;
  unsigned short* obuf = hsb;                       // hsb dead after qkv gemm

  probe_dtype<<<1, 64, 0, stream>>>((const unsigned short*)hs, flag);
  cvt_hs<<<dim3(3072), 256, 0, stream>>>(hs, hsb, flag);

  // weights -> bf16 B^T rows of WT
  tr_any<<<dim3(6, 48, 1),  256, 0, stream>>>(Wq, WT,              1536, 192,  192,  0, 0, flag);
  tr_any<<<dim3(6, 48, 1),  256, 0, stream>>>(Wk, WT + 192 * 1536, 1536, 192,  192,  0, 0, flag);
  tr_any<<<dim3(48, 48, 1), 256, 0, stream>>>(Wv, WT + 384 * 1536, 1536, 1536, 1536, 0, 0, flag);

  // fused q|k|v projection: [4096][1536] @ WT^T -> qkvb [4096][1920]
  gemm_bt<<<dim3(15, 32, 1), 256, 0, stream>>>(hsb, WT, qkvb, 4096, 1920, 1536, nullptr);

  // v columns of qkvb -> per-(b,h) [hd][l]
  tr_any<<<dim3(48, 64, 2), 256, 0, stream>>>(qkvb + 384, vT, 2048, 1536, 1920,
                                              (long long)2048 * 1920, (long long)1536 * 2048,
                                              nullptr);

  // Wo -> B^T (reuses WT region; qkv gemm already consumed it)
  tr_any<<<dim3(48, 48, 1), 256, 0, stream>>>(Wo, WT, 1536, 1536, 1536, 0, 0, flag);

  // fused causal based-attention (no LDS, no barriers)
  attn_based<<<dim3(24, 32, 1), 256, 0, stream>>>(qkvb, vT, obuf);

  // output projection -> d_out (fp32 store if flag)
  gemm_bt<<<dim3(12, 32, 1), 256, 0, stream>>>(obuf, WT, d_out, 4096, 1536, 1536, flag);
}

// Round 6
// 360.779 us; speedup vs baseline: 1.4128x; 1.0919x over previous
//
#include <hip/hip_runtime.h>

// ---- types ------------------------------------------------------------
typedef short short8 __attribute__((ext_vector_type(8)));   // 8 bf16 MFMA A/B frag
typedef float f32x4  __attribute__((ext_vector_type(4)));   // MFMA C/D frag
typedef unsigned int u32x4 __attribute__((ext_vector_type(4))); // 16B vehicle

union V16   { u32x4 v; short8 s; };
union U16x8 { u32x4 v; unsigned short u[8]; };
union FB4   { u32x4 v; float f[4]; };

__device__ inline unsigned short f2bf(float f) {
  union { float f; unsigned int u; } x; x.f = f;
  unsigned int u = x.u + 0x7fffu + ((x.u >> 16) & 1u);   // RNE
  return (unsigned short)(u >> 16);
}

// ---- dtype probe (fp32 vs bf16 inputs) --------------------------------
__global__ void probe_dtype(const unsigned short* __restrict__ hs, int* __restrict__ flag) {
  if (threadIdx.x == 0) {
    int bad = 0;
    for (int i = 0; i < 64; ++i) {
      unsigned int e = (hs[2 * i] >> 7) & 0xFFu;
      if (e >= 0xFEu || (e > 0u && e < 0x60u)) bad++;
    }
    *flag = (bad >= 6) ? 1 : 0;   // 1 => fp32
  }
}

// ---- hs -> bf16 contiguous (one-time convert; 8 el/thread) ------------
__global__ __launch_bounds__(256) void cvt_hs(const void* __restrict__ in_,
                                              unsigned short* __restrict__ out,
                                              const int* flagp) {
  const int f = *flagp;
  size_t i0 = ((size_t)blockIdx.x * 256 + threadIdx.x) * 8;
  if (f) {
    const float* in = (const float*)in_;
    FB4 a, b; a.v = *(const u32x4*)&in[i0]; b.v = *(const u32x4*)&in[i0 + 4];
    U16x8 p;
#pragma unroll
    for (int j = 0; j < 4; ++j) { p.u[j] = f2bf(a.f[j]); p.u[j + 4] = f2bf(b.f[j]); }
    *(u32x4*)&out[i0] = p.v;
  } else {
    *(u32x4*)&out[i0] = *(const u32x4*)((const unsigned short*)in_ + i0);
  }
}

// ---- transpose (+optional fp32->bf16): out[z][c][r] = bf16(in[z][r][c]) ----
__global__ __launch_bounds__(256) void tr_any(const void* __restrict__ in_,
                                              unsigned short* __restrict__ out,
                                              int R, int C, int ldin,
                                              long long in_bstride, long long out_bstride,
                                              const int* flagp) {
  __shared__ unsigned short t[32][33];
  const int f = flagp ? *flagp : 0;
  const size_t ibase = (size_t)blockIdx.z * in_bstride;
  const size_t obase = (size_t)blockIdx.z * out_bstride;
  const int tx = threadIdx.x & 31, ty = threadIdx.x >> 5;
  const int r0 = blockIdx.y * 32, c0 = blockIdx.x * 32;
#pragma unroll
  for (int i = 0; i < 4; ++i) {
    size_t idx = ibase + (size_t)(r0 + ty + 8 * i) * ldin + (c0 + tx);
    t[ty + 8 * i][tx] = f ? f2bf(((const float*)in_)[idx])
                          : ((const unsigned short*)in_)[idx];
  }
  __syncthreads();
#pragma unroll
  for (int i = 0; i < 4; ++i)
    out[obase + (size_t)(c0 + ty + 8 * i) * R + (r0 + tx)] = t[tx][ty + 8 * i];
}

// ---- C[M][N] = A[M][K] @ BT[N][K]^T, A/BT bf16; C bf16 or fp32 (oflag) ----
// 128x128 tile, BK=32, 4 waves in 2x2 quadrants of 64x64.
__global__ __launch_bounds__(256) void gemm_bt(const unsigned short* __restrict__ A,
                                               const unsigned short* __restrict__ BT,
                                               void* __restrict__ C_,
                                               int M, int N, int K,
                                               const int* oflagp) {
  __shared__ unsigned short As[128][40];  // +8 pad
  __shared__ unsigned short Bs[128][40];
  const int of = oflagp ? *oflagp : 0;
  const int m0 = blockIdx.y * 128, n0 = blockIdx.x * 128;
  const int tid = threadIdx.x;
  const int lane = tid & 63, w = tid >> 6;
  const int wr = w >> 1, wc = w & 1;
  const int quad = lane >> 4, mrow = lane & 15;

  const f32x4 zf = {0.f, 0.f, 0.f, 0.f};
  f32x4 acc[4][4];
#pragma unroll
  for (int mt = 0; mt < 4; ++mt)
#pragma unroll
    for (int nt = 0; nt < 4; ++nt) acc[mt][nt] = zf;

  for (int k0 = 0; k0 < K; k0 += 32) {
    __syncthreads();
#pragma unroll
    for (int i = 0; i < 2; ++i) {
      int slot = tid + i * 256;
      int row = slot >> 2;
      int kc = (slot & 3) << 3;
      *(u32x4*)&As[row][kc] = *(const u32x4*)&A [(size_t)(m0 + row) * K + k0 + kc];
      *(u32x4*)&Bs[row][kc] = *(const u32x4*)&BT[(size_t)(n0 + row) * K + k0 + kc];
    }
    __syncthreads();
    short8 afr[4], bfr[4];
#pragma unroll
    for (int mt = 0; mt < 4; ++mt) {
      V16 u; u.v = *(const u32x4*)&As[wr * 64 + mt * 16 + mrow][quad * 8];
      afr[mt] = u.s;
    }
#pragma unroll
    for (int nt = 0; nt < 4; ++nt) {
      V16 u; u.v = *(const u32x4*)&Bs[wc * 64 + nt * 16 + mrow][quad * 8];
      bfr[nt] = u.s;
    }
#pragma unroll
    for (int mt = 0; mt < 4; ++mt)
#pragma unroll
      for (int nt = 0; nt < 4; ++nt)
        acc[mt][nt] = __builtin_amdgcn_mfma_f32_16x16x32_bf16(afr[mt], bfr[nt], acc[mt][nt], 0, 0, 0);
  }
#pragma unroll
  for (int mt = 0; mt < 4; ++mt)
#pragma unroll
    for (int nt = 0; nt < 4; ++nt)
#pragma unroll
      for (int r = 0; r < 4; ++r) {
        int grow = m0 + wr * 64 + mt * 16 + quad * 4 + r;
        int gcol = n0 + wc * 64 + nt * 16 + mrow;
        size_t idx = (size_t)grow * N + gcol;
        if (of) ((float*)C_)[idx] = acc[mt][nt][r];
        else    ((unsigned short*)C_)[idx] = f2bf(acc[mt][nt][r]);
      }
}

// ---- fused causal "based" attention -----------------------------------
// qkv: [4096][1920] bf16 (cols 0..191 q, 192..383 k); vT: [24*128][2048]
// obuf: [4096][1536]. grid (24,32): (b*12+h, q-tile). 4 waves x 16 q-rows.
// Round-6 structure: batched vT loads (vf[2][8] regs, issued at iteration
// top, consumed ~500cyc later) + software-pipelined k-frags (prefetch kt+1
// after S-MFMAs). launch_bounds(256,3) caps VGPR ~170 (3 waves/SIMD) so the
// allocator does NOT serialize loads (round-5: 52 VGPR -> vmcnt(0) per load,
// ~12k cyc/iter, MfmaUtil 3.8%).
__global__ __launch_bounds__(256, 3) void attn_based(const unsigned short* __restrict__ qkv,
                                                     const unsigned short* __restrict__ vT,
                                                     unsigned short* __restrict__ obuf) {
  const int LD = 1920;
  const int bh = blockIdx.x;
  const int qt = 31 - blockIdx.y;         // long blocks dispatch first
  const int b = bh / 12, h = bh % 12;
  const int lane = threadIdx.x & 63, w = threadIdx.x >> 6;
  const int quad = lane >> 4, mrow = lane & 15;
  const f32x4 zf = {0.f, 0.f, 0.f, 0.f};
  const bool act = (quad < 2);

  // q B-frag (loop-invariant): B[n=q=mrow][k=feature=quad*8+j]; quads 2,3 zero
  short8 bq = {0, 0, 0, 0, 0, 0, 0, 0};
  const int q_abs = qt * 64 + w * 16 + mrow;
  if (act) {
    V16 u; u.v = *(const u32x4*)&qkv[(size_t)(b * 2048 + q_abs) * LD + h * 16 + quad * 8];
    bq = u.s;
  }

  // lane-invariant base pointers, advanced per kt
  const unsigned short* kptr = &qkv[(size_t)(b * 2048 + mrow) * LD + 192 + h * 16 + quad * 8];
  const unsigned short* vptr = &vT[(size_t)(bh * 128 + mrow) * 2048 + quad * 8];

  f32x4 oacc[8];
#pragma unroll
  for (int nt = 0; nt < 8; ++nt) oacc[nt] = zf;
  float zcol = 0.f;                        // partial z for column q = mrow

  // preload k-frags for kt=0 (rows jt*16+mrow)
  V16 kf[4];
#pragma unroll
  for (int jt = 0; jt < 4; ++jt) {
    kf[jt].s = (short8){0, 0, 0, 0, 0, 0, 0, 0};
    if (act) kf[jt].v = *(const u32x4*)(kptr + (size_t)(jt * 16) * LD);
  }

  for (int kt = 0; kt <= qt; ++kt) {
    const int kv0 = kt * 64;
    // batch-issue ALL vT loads for this iteration (consumed after poly+shfl)
    V16 vf[2][8];
#pragma unroll
    for (int c = 0; c < 2; ++c)
#pragma unroll
      for (int nt = 0; nt < 8; ++nt)
        vf[c][nt].v = *(const u32x4*)(vptr + (size_t)(nt * 16) * 2048 + kv0 + c * 32);

    // S^T tiles: A-frag = k rows (m=kv), B-frag = bq (n=q)
    f32x4 st[4];
#pragma unroll
    for (int jt = 0; jt < 4; ++jt)
      st[jt] = __builtin_amdgcn_mfma_f32_16x16x32_bf16(kf[jt].s, bq, zf, 0, 0, 0);

    // software-pipeline: prefetch kt+1's k-frags (uniform branch)
    kptr += (size_t)64 * LD;
    if (kt < qt) {
#pragma unroll
      for (int jt = 0; jt < 4; ++jt)
        if (act) kf[jt].v = *(const u32x4*)(kptr + (size_t)(jt * 16) * LD);
    }

    // poly + causal mask + z + pack: attn = 1 + 0.25*s + 0.03125*s^2
    unsigned int pk[4][2];
#pragma unroll
    for (int jt = 0; jt < 4; ++jt) {
      const int kvb = kv0 + jt * 16 + quad * 4;
#pragma unroll
      for (int r2 = 0; r2 < 2; ++r2) {
        float s0 = st[jt][2 * r2], s1 = st[jt][2 * r2 + 1];
        float a0 = fmaf(s0, fmaf(s0, 0.03125f, 0.25f), 1.0f);
        float a1 = fmaf(s1, fmaf(s1, 0.03125f, 0.25f), 1.0f);
        a0 = (kvb + 2 * r2     <= q_abs) ? a0 : 0.0f;
        a1 = (kvb + 2 * r2 + 1 <= q_abs) ? a1 : 0.0f;
        zcol += a0 + a1;
        pk[jt][r2] = (unsigned int)f2bf(a0) | ((unsigned int)f2bf(a1) << 16);
      }
    }
    // wave transpose C/D -> A layout + PV MFMAs (consume vf)
#pragma unroll
    for (int c = 0; c < 2; ++c) {
      union { short8 s; int wd[4]; } ap;
#pragma unroll
      for (int t = 0; t < 4; ++t) {
        int src = (2 * (quad & 1) + (t >> 1)) * 16 + mrow;
        int v0 = __shfl((int)pk[2 * c][t & 1], src, 64);
        int v1 = __shfl((int)pk[2 * c + 1][t & 1], src, 64);
        ap.wd[t] = (quad >> 1) ? v1 : v0;
      }
#pragma unroll
      for (int nt = 0; nt < 8; ++nt)
        oacc[nt] = __builtin_amdgcn_mfma_f32_16x16x32_bf16(ap.s, vf[c][nt].s, oacc[nt], 0, 0, 0);
    }
  }
  // z: reduce partial column sums across quads; broadcast to O rows
  zcol += __shfl_xor(zcol, 16, 64);
  zcol += __shfl_xor(zcol, 32, 64);
  float inv[4];
#pragma unroll
  for (int r = 0; r < 4; ++r)
    inv[r] = 1.0f / (__shfl(zcol, quad * 4 + r, 64) + 1e-12f);
#pragma unroll
  for (int nt = 0; nt < 8; ++nt)
#pragma unroll
    for (int r = 0; r < 4; ++r)
      obuf[(size_t)(b * 2048 + qt * 64 + w * 16 + quad * 4 + r) * 1536 +
           h * 128 + nt * 16 + mrow] = f2bf(oacc[nt][r] * inv[r]);
}

// ---- launch -----------------------------------------------------------
extern "C" void kernel_launch(void* const* d_in, const int* in_sizes, int n_in,
                              void* d_out, int out_size, void* d_ws, size_t ws_size,
                              hipStream_t stream) {
  const void* hs = d_in[0];
  const void* Wq = d_in[1];
  const void* Wk = d_in[2];
  const void* Wv = d_in[3];
  const void* Wo = d_in[4];

  // ws (~46.8 MB): flag | WT[1920][1536] | qkvb[4096][1920] | hsb[4096][1536] | vT[24*128][2048]
  int* flag = (int*)d_ws;
  unsigned short* ws   = (unsigned short*)d_ws + 128;
  unsigned short* WT   = ws;                        // q rows 0..191, k 192..383, v 384..1919
  unsigned short* qkvb = WT + 1920 * 1536;
  unsigned short* hsb  = qkvb + 4096 * 1920;
  unsigned short* vT   = hsb + 4096 * 1536;
  unsigned short* obuf = hsb;                       // hsb dead after qkv gemm

  probe_dtype<<<1, 64, 0, stream>>>((const unsigned short*)hs, flag);
  cvt_hs<<<dim3(3072), 256, 0, stream>>>(hs, hsb, flag);

  // weights -> bf16 B^T rows of WT
  tr_any<<<dim3(6, 48, 1),  256, 0, stream>>>(Wq, WT,              1536, 192,  192,  0, 0, flag);
  tr_any<<<dim3(6, 48, 1),  256, 0, stream>>>(Wk, WT + 192 * 1536, 1536, 192,  192,  0, 0, flag);
  tr_any<<<dim3(48, 48, 1), 256, 0, stream>>>(Wv, WT + 384 * 1536, 1536, 1536, 1536, 0, 0, flag);

  // fused q|k|v projection: [4096][1536] @ WT^T -> qkvb [4096][1920]
  gemm_bt<<<dim3(15, 32, 1), 256, 0, stream>>>(hsb, WT, qkvb, 4096, 1920, 1536, nullptr);

  // v columns of qkvb -> per-(b,h) [hd][l]
  tr_any<<<dim3(48, 64, 2), 256, 0, stream>>>(qkvb + 384, vT, 2048, 1536, 1920,
                                              (long long)2048 * 1920, (long long)1536 * 2048,
                                              nullptr);

  // Wo -> B^T (reuses WT region; qkv gemm already consumed it)
  tr_any<<<dim3(48, 48, 1), 256, 0, stream>>>(Wo, WT, 1536, 1536, 1536, 0, 0, flag);

  // fused causal based-attention
  attn_based<<<dim3(24, 32, 1), 256, 0, stream>>>(qkvb, vT, obuf);

  // output projection -> d_out (fp32 store if flag)
  gemm_bt<<<dim3(12, 32, 1), 256, 0, stream>>>(obuf, WT, d_out, 4096, 1536, 1536, flag);
}

// Round 7
// 281.563 us; speedup vs baseline: 1.8102x; 1.2813x over previous
//
#include <hip/hip_runtime.h>

// ---- types ------------------------------------------------------------
typedef short short8 __attribute__((ext_vector_type(8)));   // 8 bf16 MFMA A/B frag
typedef float f32x4  __attribute__((ext_vector_type(4)));   // MFMA C/D frag
typedef unsigned int u32x4 __attribute__((ext_vector_type(4))); // 16B vehicle

union V16   { u32x4 v; short8 s; };
union U16x8 { u32x4 v; unsigned short u[8]; };
union FB4   { u32x4 v; float f[4]; };

__device__ inline unsigned short f2bf(float f) {
  union { float f; unsigned int u; } x; x.f = f;
  unsigned int u = x.u + 0x7fffu + ((x.u >> 16) & 1u);   // RNE
  return (unsigned short)(u >> 16);
}

// ---- dtype probe (fp32 vs bf16 inputs) --------------------------------
__global__ void probe_dtype(const unsigned short* __restrict__ hs, int* __restrict__ flag) {
  if (threadIdx.x == 0) {
    int bad = 0;
    for (int i = 0; i < 64; ++i) {
      unsigned int e = (hs[2 * i] >> 7) & 0xFFu;
      if (e >= 0xFEu || (e > 0u && e < 0x60u)) bad++;
    }
    *flag = (bad >= 6) ? 1 : 0;   // 1 => fp32
  }
}

// ---- hs -> bf16 contiguous (one-time convert; 8 el/thread) ------------
__global__ __launch_bounds__(256) void cvt_hs(const void* __restrict__ in_,
                                              unsigned short* __restrict__ out,
                                              const int* flagp) {
  const int f = *flagp;
  size_t i0 = ((size_t)blockIdx.x * 256 + threadIdx.x) * 8;
  if (f) {
    const float* in = (const float*)in_;
    FB4 a, b; a.v = *(const u32x4*)&in[i0]; b.v = *(const u32x4*)&in[i0 + 4];
    U16x8 p;
#pragma unroll
    for (int j = 0; j < 4; ++j) { p.u[j] = f2bf(a.f[j]); p.u[j + 4] = f2bf(b.f[j]); }
    *(u32x4*)&out[i0] = p.v;
  } else {
    *(u32x4*)&out[i0] = *(const u32x4*)((const unsigned short*)in_ + i0);
  }
}

// ---- transpose (+optional fp32->bf16): out[z][c][r] = bf16(in[z][r][c]) ----
__global__ __launch_bounds__(256) void tr_any(const void* __restrict__ in_,
                                              unsigned short* __restrict__ out,
                                              int R, int C, int ldin,
                                              long long in_bstride, long long out_bstride,
                                              const int* flagp) {
  __shared__ unsigned short t[32][33];
  const int f = flagp ? *flagp : 0;
  const size_t ibase = (size_t)blockIdx.z * in_bstride;
  const size_t obase = (size_t)blockIdx.z * out_bstride;
  const int tx = threadIdx.x & 31, ty = threadIdx.x >> 5;
  const int r0 = blockIdx.y * 32, c0 = blockIdx.x * 32;
#pragma unroll
  for (int i = 0; i < 4; ++i) {
    size_t idx = ibase + (size_t)(r0 + ty + 8 * i) * ldin + (c0 + tx);
    t[ty + 8 * i][tx] = f ? f2bf(((const float*)in_)[idx])
                          : ((const unsigned short*)in_)[idx];
  }
  __syncthreads();
#pragma unroll
  for (int i = 0; i < 4; ++i)
    out[obase + (size_t)(c0 + ty + 8 * i) * R + (r0 + tx)] = t[tx][ty + 8 * i];
}

// ---- C[M][N] = A[M][K] @ BT[N][K]^T, A/BT bf16; C bf16 or fp32 (oflag) ----
// 128x128 tile, BK=32, 4 waves in 2x2 quadrants of 64x64.
__global__ __launch_bounds__(256) void gemm_bt(const unsigned short* __restrict__ A,
                                               const unsigned short* __restrict__ BT,
                                               void* __restrict__ C_,
                                               int M, int N, int K,
                                               const int* oflagp) {
  __shared__ unsigned short As[128][40];  // +8 pad
  __shared__ unsigned short Bs[128][40];
  const int of = oflagp ? *oflagp : 0;
  const int m0 = blockIdx.y * 128, n0 = blockIdx.x * 128;
  const int tid = threadIdx.x;
  const int lane = tid & 63, w = tid >> 6;
  const int wr = w >> 1, wc = w & 1;
  const int quad = lane >> 4, mrow = lane & 15;

  const f32x4 zf = {0.f, 0.f, 0.f, 0.f};
  f32x4 acc[4][4];
#pragma unroll
  for (int mt = 0; mt < 4; ++mt)
#pragma unroll
    for (int nt = 0; nt < 4; ++nt) acc[mt][nt] = zf;

  for (int k0 = 0; k0 < K; k0 += 32) {
    __syncthreads();
#pragma unroll
    for (int i = 0; i < 2; ++i) {
      int slot = tid + i * 256;
      int row = slot >> 2;
      int kc = (slot & 3) << 3;
      *(u32x4*)&As[row][kc] = *(const u32x4*)&A [(size_t)(m0 + row) * K + k0 + kc];
      *(u32x4*)&Bs[row][kc] = *(const u32x4*)&BT[(size_t)(n0 + row) * K + k0 + kc];
    }
    __syncthreads();
    short8 afr[4], bfr[4];
#pragma unroll
    for (int mt = 0; mt < 4; ++mt) {
      V16 u; u.v = *(const u32x4*)&As[wr * 64 + mt * 16 + mrow][quad * 8];
      afr[mt] = u.s;
    }
#pragma unroll
    for (int nt = 0; nt < 4; ++nt) {
      V16 u; u.v = *(const u32x4*)&Bs[wc * 64 + nt * 16 + mrow][quad * 8];
      bfr[nt] = u.s;
    }
#pragma unroll
    for (int mt = 0; mt < 4; ++mt)
#pragma unroll
      for (int nt = 0; nt < 4; ++nt)
        acc[mt][nt] = __builtin_amdgcn_mfma_f32_16x16x32_bf16(afr[mt], bfr[nt], acc[mt][nt], 0, 0, 0);
  }
#pragma unroll
  for (int mt = 0; mt < 4; ++mt)
#pragma unroll
    for (int nt = 0; nt < 4; ++nt)
#pragma unroll
      for (int r = 0; r < 4; ++r) {
        int grow = m0 + wr * 64 + mt * 16 + quad * 4 + r;
        int gcol = n0 + wc * 64 + nt * 16 + mrow;
        size_t idx = (size_t)grow * N + gcol;
        if (of) ((float*)C_)[idx] = acc[mt][nt][r];
        else    ((unsigned short*)C_)[idx] = f2bf(acc[mt][nt][r]);
      }
}

// ---- fused causal "based" attention — LDS-staged V, double-buffered ----
// qkv: [4096][1920] bf16 (cols 0..191 q, 192..383 k); vT: [24*128][2048]
// obuf: [4096][1536]. grid (24,32): (b*12+h, q-tile). 4 waves x 16 q-rows.
// Round-7: V tile (64 kv x 128 hd, shared by all 4 waves) staged through LDS
// double buffer. Staging global loads issue at iteration top, ds_write ~600cyc
// later, barrier once per iteration. PV B-frags via ds_read_b128 (~120cyc,
// pipelined) instead of serialized global loads (round-6: compiler sank the
// vf[2][8] batch to just-before-use -> 20x ~600cyc serial stalls, 84 VGPR).
__global__ __launch_bounds__(256, 3) void attn_based(const unsigned short* __restrict__ qkv,
                                                     const unsigned short* __restrict__ vT,
                                                     unsigned short* __restrict__ obuf) {
  __shared__ unsigned short Vs[2][128][72];  // +8 pad: 16B-aligned rows, spread banks
  const int LD = 1920;
  const int bh = blockIdx.x;
  const int qt = 31 - blockIdx.y;            // long blocks dispatch first (LPT)
  const int b = bh / 12, h = bh % 12;
  const int tid = threadIdx.x;
  const int lane = tid & 63, w = tid >> 6;
  const int quad = lane >> 4, mrow = lane & 15;
  const f32x4 zf = {0.f, 0.f, 0.f, 0.f};
  const bool act = (quad < 2);

  // q B-frag (loop-invariant): B[n=q=mrow][k=feature=quad*8+j]; quads 2,3 zero
  short8 bq = {0, 0, 0, 0, 0, 0, 0, 0};
  const int q_abs = qt * 64 + w * 16 + mrow;
  if (act) {
    V16 u; u.v = *(const u32x4*)&qkv[(size_t)(b * 2048 + q_abs) * LD + h * 16 + quad * 8];
    bq = u.s;
  }

  // staging slot map: slot s = tid + 256*i -> hd = s>>3, kv-chunk = s&7
  // (8 lanes cover one 128B vT row segment: fully coalesced)
  const int hd_s = tid >> 3, kvc_s = tid & 7;
  const unsigned short* vsbase = vT + (size_t)(bh * 128 + hd_s) * 2048 + kvc_s * 8;

  // k-frag pointer (rows jt*16+mrow of k block), advanced per kt
  const unsigned short* kptr = &qkv[(size_t)(b * 2048 + mrow) * LD + 192 + h * 16 + quad * 8];

  f32x4 oacc[8];
#pragma unroll
  for (int nt = 0; nt < 8; ++nt) oacc[nt] = zf;
  float zcol = 0.f;                          // partial z for column q = mrow

  // prologue: stage V tile 0, preload k-frags for kt=0
  u32x4 sreg[4];
#pragma unroll
  for (int i = 0; i < 4; ++i)
    sreg[i] = *(const u32x4*)(vsbase + (size_t)(32 * i) * 2048);
  V16 kf[4];
#pragma unroll
  for (int jt = 0; jt < 4; ++jt) {
    kf[jt].s = (short8){0, 0, 0, 0, 0, 0, 0, 0};
    if (act) kf[jt].v = *(const u32x4*)(kptr + (size_t)(jt * 16) * LD);
  }
#pragma unroll
  for (int i = 0; i < 4; ++i)
    *(u32x4*)&Vs[0][hd_s + 32 * i][kvc_s * 8] = sreg[i];
  __syncthreads();

  for (int kt = 0; kt <= qt; ++kt) {
    const int kv0 = kt * 64;
    const int cur = kt & 1;
    // issue next tile's staging loads (consumed by ds_write at iteration end)
    if (kt < qt) {
#pragma unroll
      for (int i = 0; i < 4; ++i)
        sreg[i] = *(const u32x4*)(vsbase + (size_t)(32 * i) * 2048 + kv0 + 64);
    }

    // S^T tiles: A-frag = k rows (m=kv), B-frag = bq (n=q)
    f32x4 st[4];
#pragma unroll
    for (int jt = 0; jt < 4; ++jt)
      st[jt] = __builtin_amdgcn_mfma_f32_16x16x32_bf16(kf[jt].s, bq, zf, 0, 0, 0);

    // software-pipeline k-frags for kt+1
    kptr += (size_t)64 * LD;
    if (kt < qt) {
#pragma unroll
      for (int jt = 0; jt < 4; ++jt)
        if (act) kf[jt].v = *(const u32x4*)(kptr + (size_t)(jt * 16) * LD);
    }

    // poly + causal mask + z + pack: attn = 1 + 0.25*s + 0.03125*s^2
    unsigned int pk[4][2];
#pragma unroll
    for (int jt = 0; jt < 4; ++jt) {
      const int kvb = kv0 + jt * 16 + quad * 4;
#pragma unroll
      for (int r2 = 0; r2 < 2; ++r2) {
        float s0 = st[jt][2 * r2], s1 = st[jt][2 * r2 + 1];
        float a0 = fmaf(s0, fmaf(s0, 0.03125f, 0.25f), 1.0f);
        float a1 = fmaf(s1, fmaf(s1, 0.03125f, 0.25f), 1.0f);
        a0 = (kvb + 2 * r2     <= q_abs) ? a0 : 0.0f;
        a1 = (kvb + 2 * r2 + 1 <= q_abs) ? a1 : 0.0f;
        zcol += a0 + a1;
        pk[jt][r2] = (unsigned int)f2bf(a0) | ((unsigned int)f2bf(a1) << 16);
      }
    }
    // wave transpose C/D -> A layout + PV MFMAs (B-frags from LDS)
#pragma unroll
    for (int c = 0; c < 2; ++c) {
      union { short8 s; int wd[4]; } ap;
#pragma unroll
      for (int t = 0; t < 4; ++t) {
        int src = (2 * (quad & 1) + (t >> 1)) * 16 + mrow;
        int v0 = __shfl((int)pk[2 * c][t & 1], src, 64);
        int v1 = __shfl((int)pk[2 * c + 1][t & 1], src, 64);
        ap.wd[t] = (quad >> 1) ? v1 : v0;
      }
#pragma unroll
      for (int nt = 0; nt < 8; ++nt) {
        V16 u; u.v = *(const u32x4*)&Vs[cur][nt * 16 + mrow][c * 32 + quad * 8];
        oacc[nt] = __builtin_amdgcn_mfma_f32_16x16x32_bf16(ap.s, u.s, oacc[nt], 0, 0, 0);
      }
    }
    // commit next tile to the other buffer; one barrier per iteration
    if (kt < qt) {
#pragma unroll
      for (int i = 0; i < 4; ++i)
        *(u32x4*)&Vs[cur ^ 1][hd_s + 32 * i][kvc_s * 8] = sreg[i];
    }
    __syncthreads();
  }
  // z: reduce partial column sums across quads; broadcast to O rows
  zcol += __shfl_xor(zcol, 16, 64);
  zcol += __shfl_xor(zcol, 32, 64);
  float inv[4];
#pragma unroll
  for (int r = 0; r < 4; ++r)
    inv[r] = 1.0f / (__shfl(zcol, quad * 4 + r, 64) + 1e-12f);
#pragma unroll
  for (int nt = 0; nt < 8; ++nt)
#pragma unroll
    for (int r = 0; r < 4; ++r)
      obuf[(size_t)(b * 2048 + qt * 64 + w * 16 + quad * 4 + r) * 1536 +
           h * 128 + nt * 16 + mrow] = f2bf(oacc[nt][r] * inv[r]);
}

// ---- launch -----------------------------------------------------------
extern "C" void kernel_launch(void* const* d_in, const int* in_sizes, int n_in,
                              void* d_out, int out_size, void* d_ws, size_t ws_size,
                              hipStream_t stream) {
  const void* hs = d_in[0];
  const void* Wq = d_in[1];
  const void* Wk = d_in[2];
  const void* Wv = d_in[3];
  const void* Wo = d_in[4];

  // ws (~46.8 MB): flag | WT[1920][1536] | qkvb[4096][1920] | hsb[4096][1536] | vT[24*128][2048]
  int* flag = (int*)d_ws;
  unsigned short* ws   = (unsigned short*)d_ws + 128;
  unsigned short* WT   = ws;                        // q rows 0..191, k 192..383, v 384..1919
  unsigned short* qkvb = WT + 1920 * 1536;
  unsigned short* hsb  = qkvb + 4096 * 1920;
  unsigned short* vT   = hsb + 4096 * 1536;
  unsigned short* obuf = hsb;                       // hsb dead after qkv gemm

  probe_dtype<<<1, 64, 0, stream>>>((const unsigned short*)hs, flag);
  cvt_hs<<<dim3(3072), 256, 0, stream>>>(hs, hsb, flag);

  // weights -> bf16 B^T rows of WT
  tr_any<<<dim3(6, 48, 1),  256, 0, stream>>>(Wq, WT,              1536, 192,  192,  0, 0, flag);
  tr_any<<<dim3(6, 48, 1),  256, 0, stream>>>(Wk, WT + 192 * 1536, 1536, 192,  192,  0, 0, flag);
  tr_any<<<dim3(48, 48, 1), 256, 0, stream>>>(Wv, WT + 384 * 1536, 1536, 1536, 1536, 0, 0, flag);

  // fused q|k|v projection: [4096][1536] @ WT^T -> qkvb [4096][1920]
  gemm_bt<<<dim3(15, 32, 1), 256, 0, stream>>>(hsb, WT, qkvb, 4096, 1920, 1536, nullptr);

  // v columns of qkvb -> per-(b,h) [hd][l]
  tr_any<<<dim3(48, 64, 2), 256, 0, stream>>>(qkvb + 384, vT, 2048, 1536, 1920,
                                              (long long)2048 * 1920, (long long)1536 * 2048,
                                              nullptr);

  // Wo -> B^T (reuses WT region; qkv gemm already consumed it)
  tr_any<<<dim3(48, 48, 1), 256, 0, stream>>>(Wo, WT, 1536, 1536, 1536, 0, 0, flag);

  // fused causal based-attention (LDS-staged V)
  attn_based<<<dim3(24, 32, 1), 256, 0, stream>>>(qkvb, vT, obuf);

  // output projection -> d_out (fp32 store if flag)
  gemm_bt<<<dim3(12, 32, 1), 256, 0, stream>>>(obuf, WT, d_out, 4096, 1536, 1536, flag);
}

// Round 8
// 257.592 us; speedup vs baseline: 1.9787x; 1.0931x over previous
//
#include <hip/hip_runtime.h>

// ---- types ------------------------------------------------------------
typedef short short8 __attribute__((ext_vector_type(8)));   // 8 bf16 MFMA A/B frag
typedef float f32x4  __attribute__((ext_vector_type(4)));   // MFMA C/D frag
typedef unsigned int u32x4 __attribute__((ext_vector_type(4))); // 16B vehicle

union V16   { u32x4 v; short8 s; };
union U16x8 { u32x4 v; unsigned short u[8]; };
union FB4   { u32x4 v; float f[4]; };

__device__ inline unsigned short f2bf(float f) {
  union { float f; unsigned int u; } x; x.f = f;
  unsigned int u = x.u + 0x7fffu + ((x.u >> 16) & 1u);   // RNE
  return (unsigned short)(u >> 16);
}

// async global->LDS DMA, 16B/lane; LDS dest = wave-uniform base + lane*16
__device__ __forceinline__ void gl_lds16(const unsigned short* g, unsigned short* l) {
  __builtin_amdgcn_global_load_lds(
      (const __attribute__((address_space(1))) unsigned int*)g,
      (__attribute__((address_space(3))) unsigned int*)l, 16, 0, 0);
}

// ---- dtype probe (fp32 vs bf16 inputs) --------------------------------
__global__ void probe_dtype(const unsigned short* __restrict__ hs, int* __restrict__ flag) {
  if (threadIdx.x == 0) {
    int bad = 0;
    for (int i = 0; i < 64; ++i) {
      unsigned int e = (hs[2 * i] >> 7) & 0xFFu;
      if (e >= 0xFEu || (e > 0u && e < 0x60u)) bad++;
    }
    *flag = (bad >= 6) ? 1 : 0;   // 1 => fp32
  }
}

// ---- hs -> bf16 contiguous (one-time convert; 8 el/thread) ------------
__global__ __launch_bounds__(256) void cvt_hs(const void* __restrict__ in_,
                                              unsigned short* __restrict__ out,
                                              const int* flagp) {
  const int f = *flagp;
  size_t i0 = ((size_t)blockIdx.x * 256 + threadIdx.x) * 8;
  if (f) {
    const float* in = (const float*)in_;
    FB4 a, b; a.v = *(const u32x4*)&in[i0]; b.v = *(const u32x4*)&in[i0 + 4];
    U16x8 p;
#pragma unroll
    for (int j = 0; j < 4; ++j) { p.u[j] = f2bf(a.f[j]); p.u[j + 4] = f2bf(b.f[j]); }
    *(u32x4*)&out[i0] = p.v;
  } else {
    *(u32x4*)&out[i0] = *(const u32x4*)((const unsigned short*)in_ + i0);
  }
}

// ---- transpose (+optional fp32->bf16): out[z][c][r] = bf16(in[z][r][c]) ----
__global__ __launch_bounds__(256) void tr_any(const void* __restrict__ in_,
                                              unsigned short* __restrict__ out,
                                              int R, int C, int ldin,
                                              long long in_bstride, long long out_bstride,
                                              const int* flagp) {
  __shared__ unsigned short t[32][33];
  const int f = flagp ? *flagp : 0;
  const size_t ibase = (size_t)blockIdx.z * in_bstride;
  const size_t obase = (size_t)blockIdx.z * out_bstride;
  const int tx = threadIdx.x & 31, ty = threadIdx.x >> 5;
  const int r0 = blockIdx.y * 32, c0 = blockIdx.x * 32;
#pragma unroll
  for (int i = 0; i < 4; ++i) {
    size_t idx = ibase + (size_t)(r0 + ty + 8 * i) * ldin + (c0 + tx);
    t[ty + 8 * i][tx] = f ? f2bf(((const float*)in_)[idx])
                          : ((const unsigned short*)in_)[idx];
  }
  __syncthreads();
#pragma unroll
  for (int i = 0; i < 4; ++i)
    out[obase + (size_t)(c0 + ty + 8 * i) * R + (r0 + tx)] = t[tx][ty + 8 * i];
}

// ---- C[M][N] = A[M][K] @ BT[N][K]^T, A/BT bf16; C bf16 or fp32 (oflag) ----
// m97-style: unpadded LDS tiles filled by global_load_lds(16B), XOR-swizzled
// on the GLOBAL side (physical chunk l&3 holds logical (l&3)^((l>>3)&3)) so
// frag ds_read_b128 start banks spread 8-wide -> 2-way (free). 128x128 tile,
// BK=32, 4 waves in 2x2 quadrants of 64x64.
__global__ __launch_bounds__(256) void gemm_bt(const unsigned short* __restrict__ A,
                                               const unsigned short* __restrict__ BT,
                                               void* __restrict__ C_,
                                               int M, int N, int K,
                                               const int* oflagp) {
  __shared__ unsigned short As[128][32];
  __shared__ unsigned short Bs[128][32];
  const int of = oflagp ? *oflagp : 0;
  const int m0 = blockIdx.y * 128, n0 = blockIdx.x * 128;
  const int tid = threadIdx.x;
  const int lane = tid & 63, w = tid >> 6;
  const int wr = w >> 1, wc = w & 1;
  const int quad = lane >> 4, mrow = lane & 15;

  // staging map: load j covers rows 32w+16j+ (lane>>2); swizzled global chunk
  const int sr = lane >> 2;
  const int sc = ((lane & 3) ^ ((lane >> 3) & 3)) * 8;   // shorts
  const int fsw = ((mrow >> 1) & 3);                     // frag-read swizzle

  const f32x4 zf = {0.f, 0.f, 0.f, 0.f};
  f32x4 acc[4][4];
#pragma unroll
  for (int mt = 0; mt < 4; ++mt)
#pragma unroll
    for (int nt = 0; nt < 4; ++nt) acc[mt][nt] = zf;

  for (int k0 = 0; k0 < K; k0 += 32) {
    __syncthreads();                 // prior frag reads complete
#pragma unroll
    for (int j = 0; j < 2; ++j) {
      const int r = 32 * w + 16 * j + sr;
      gl_lds16(&A [(size_t)(m0 + r) * K + k0 + sc], &As[32 * w + 16 * j][0]);
      gl_lds16(&BT[(size_t)(n0 + r) * K + k0 + sc], &Bs[32 * w + 16 * j][0]);
    }
    __syncthreads();                 // DMA drained (vmcnt before barrier)
    short8 afr[4], bfr[4];
#pragma unroll
    for (int mt = 0; mt < 4; ++mt) {
      V16 u; u.v = *(const u32x4*)&As[wr * 64 + mt * 16 + mrow][(quad ^ fsw) * 8];
      afr[mt] = u.s;
    }
#pragma unroll
    for (int nt = 0; nt < 4; ++nt) {
      V16 u; u.v = *(const u32x4*)&Bs[wc * 64 + nt * 16 + mrow][(quad ^ fsw) * 8];
      bfr[nt] = u.s;
    }
#pragma unroll
    for (int mt = 0; mt < 4; ++mt)
#pragma unroll
      for (int nt = 0; nt < 4; ++nt)
        acc[mt][nt] = __builtin_amdgcn_mfma_f32_16x16x32_bf16(afr[mt], bfr[nt], acc[mt][nt], 0, 0, 0);
  }
#pragma unroll
  for (int mt = 0; mt < 4; ++mt)
#pragma unroll
    for (int nt = 0; nt < 4; ++nt)
#pragma unroll
      for (int r = 0; r < 4; ++r) {
        int grow = m0 + wr * 64 + mt * 16 + quad * 4 + r;
        int gcol = n0 + wc * 64 + nt * 16 + mrow;
        size_t idx = (size_t)grow * N + gcol;
        if (of) ((float*)C_)[idx] = acc[mt][nt][r];
        else    ((unsigned short*)C_)[idx] = f2bf(acc[mt][nt][r]);
      }
}

// ---- fused causal "based" attention — DMA-staged V, double-buffered ----
// qkv: [4096][1920] bf16 (cols 0..191 q, 192..383 k); vT: [24*128][2048]
// obuf: [4096][1536]. grid (24,32): (b*12+h, q-tile). 4 waves x 16 q-rows.
// Round-8: V staged via global_load_lds into unpadded Vs[2][128][64] with
// global-side XOR swizzle s(r)=r&7 (physical chunk l&7 <- logical (l&7)^(l>>3));
// frag reads probe (c*4+quad)^(mrow&7) -> 2-way banks (free). Removes the
// round-7 8-way staging-write conflicts (4.87M cycles) + VGPR round-trip.
__global__ __launch_bounds__(256, 3) void attn_based(const unsigned short* __restrict__ qkv,
                                                     const unsigned short* __restrict__ vT,
                                                     unsigned short* __restrict__ obuf) {
  __shared__ unsigned short Vs[2][128][64];  // unpadded (DMA dest), 32 KB
  const int LD = 1920;
  const int bh = blockIdx.x;
  const int qt = 31 - blockIdx.y;            // long blocks dispatch first (LPT)
  const int b = bh / 12, h = bh % 12;
  const int tid = threadIdx.x;
  const int lane = tid & 63, w = tid >> 6;
  const int quad = lane >> 4, mrow = lane & 15;
  const f32x4 zf = {0.f, 0.f, 0.f, 0.f};
  const bool act = (quad < 2);

  // q B-frag (loop-invariant): B[n=q=mrow][k=feature=quad*8+j]; quads 2,3 zero
  short8 bq = {0, 0, 0, 0, 0, 0, 0, 0};
  const int q_abs = qt * 64 + w * 16 + mrow;
  if (act) {
    V16 u; u.v = *(const u32x4*)&qkv[(size_t)(b * 2048 + q_abs) * LD + h * 16 + quad * 8];
    bq = u.s;
  }

  // V staging map: load j covers rows 32w+8j+(lane>>3); swizzled global chunk
  const int vr = lane >> 3;                                // 0..7
  const int vc = ((lane & 7) ^ (lane >> 3)) * 8;           // shorts
  const unsigned short* vbase = vT + (size_t)(bh * 128) * 2048;

  // k-frag pointer (rows jt*16+mrow of k block), advanced per kt
  const unsigned short* kptr = &qkv[(size_t)(b * 2048 + mrow) * LD + 192 + h * 16 + quad * 8];

  f32x4 oacc[8];
#pragma unroll
  for (int nt = 0; nt < 8; ++nt) oacc[nt] = zf;
  float zcol = 0.f;                          // partial z for column q = mrow

  // prologue: DMA-stage V tile 0, preload k-frags for kt=0
#pragma unroll
  for (int j = 0; j < 4; ++j)
    gl_lds16(vbase + (size_t)(32 * w + 8 * j + vr) * 2048 + vc, &Vs[0][32 * w + 8 * j][0]);
  V16 kf[4];
#pragma unroll
  for (int jt = 0; jt < 4; ++jt) {
    kf[jt].s = (short8){0, 0, 0, 0, 0, 0, 0, 0};
    if (act) kf[jt].v = *(const u32x4*)(kptr + (size_t)(jt * 16) * LD);
  }
  __syncthreads();

  for (int kt = 0; kt <= qt; ++kt) {
    const int kv0 = kt * 64;
    const int cur = kt & 1;
    // DMA-stage next tile into the other buffer (uniform branch)
    if (kt < qt) {
#pragma unroll
      for (int j = 0; j < 4; ++j)
        gl_lds16(vbase + (size_t)(32 * w + 8 * j + vr) * 2048 + kv0 + 64 + vc,
                 &Vs[cur ^ 1][32 * w + 8 * j][0]);
    }

    // S^T tiles: A-frag = k rows (m=kv), B-frag = bq (n=q)
    f32x4 st[4];
#pragma unroll
    for (int jt = 0; jt < 4; ++jt)
      st[jt] = __builtin_amdgcn_mfma_f32_16x16x32_bf16(kf[jt].s, bq, zf, 0, 0, 0);

    // software-pipeline k-frags for kt+1
    kptr += (size_t)64 * LD;
    if (kt < qt) {
#pragma unroll
      for (int jt = 0; jt < 4; ++jt)
        if (act) kf[jt].v = *(const u32x4*)(kptr + (size_t)(jt * 16) * LD);
    }

    // poly + causal mask + z + pack: attn = 1 + 0.25*s + 0.03125*s^2
    unsigned int pk[4][2];
#pragma unroll
    for (int jt = 0; jt < 4; ++jt) {
      const int kvb = kv0 + jt * 16 + quad * 4;
#pragma unroll
      for (int r2 = 0; r2 < 2; ++r2) {
        float s0 = st[jt][2 * r2], s1 = st[jt][2 * r2 + 1];
        float a0 = fmaf(s0, fmaf(s0, 0.03125f, 0.25f), 1.0f);
        float a1 = fmaf(s1, fmaf(s1, 0.03125f, 0.25f), 1.0f);
        a0 = (kvb + 2 * r2     <= q_abs) ? a0 : 0.0f;
        a1 = (kvb + 2 * r2 + 1 <= q_abs) ? a1 : 0.0f;
        zcol += a0 + a1;
        pk[jt][r2] = (unsigned int)f2bf(a0) | ((unsigned int)f2bf(a1) << 16);
      }
    }
    // wave transpose C/D -> A layout + PV MFMAs (B-frags from swizzled LDS)
#pragma unroll
    for (int c = 0; c < 2; ++c) {
      union { short8 s; int wd[4]; } ap;
#pragma unroll
      for (int t = 0; t < 4; ++t) {
        int src = (2 * (quad & 1) + (t >> 1)) * 16 + mrow;
        int v0 = __shfl((int)pk[2 * c][t & 1], src, 64);
        int v1 = __shfl((int)pk[2 * c + 1][t & 1], src, 64);
        ap.wd[t] = (quad >> 1) ? v1 : v0;
      }
#pragma unroll
      for (int nt = 0; nt < 8; ++nt) {
        V16 u;
        u.v = *(const u32x4*)&Vs[cur][nt * 16 + mrow][((c * 4 + quad) ^ (mrow & 7)) * 8];
        oacc[nt] = __builtin_amdgcn_mfma_f32_16x16x32_bf16(ap.s, u.s, oacc[nt], 0, 0, 0);
      }
    }
    __syncthreads();   // drains DMA (vmcnt) + separates buffer reuse
  }
  // z: reduce partial column sums across quads; broadcast to O rows
  zcol += __shfl_xor(zcol, 16, 64);
  zcol += __shfl_xor(zcol, 32, 64);
  float inv[4];
#pragma unroll
  for (int r = 0; r < 4; ++r)
    inv[r] = 1.0f / (__shfl(zcol, quad * 4 + r, 64) + 1e-12f);
#pragma unroll
  for (int nt = 0; nt < 8; ++nt)
#pragma unroll
    for (int r = 0; r < 4; ++r)
      obuf[(size_t)(b * 2048 + qt * 64 + w * 16 + quad * 4 + r) * 1536 +
           h * 128 + nt * 16 + mrow] = f2bf(oacc[nt][r] * inv[r]);
}

// ---- launch -----------------------------------------------------------
extern "C" void kernel_launch(void* const* d_in, const int* in_sizes, int n_in,
                              void* d_out, int out_size, void* d_ws, size_t ws_size,
                              hipStream_t stream) {
  const void* hs = d_in[0];
  const void* Wq = d_in[1];
  const void* Wk = d_in[2];
  const void* Wv = d_in[3];
  const void* Wo = d_in[4];

  // ws (~46.8 MB): flag | WT[1920][1536] | qkvb[4096][1920] | hsb[4096][1536] | vT[24*128][2048]
  int* flag = (int*)d_ws;
  unsigned short* ws   = (unsigned short*)d_ws + 128;
  unsigned short* WT   = ws;                        // q rows 0..191, k 192..383, v 384..1919
  unsigned short* qkvb = WT + 1920 * 1536;
  unsigned short* hsb  = qkvb + 4096 * 1920;
  unsigned short* vT   = hsb + 4096 * 1536;
  unsigned short* obuf = hsb;                       // hsb dead after qkv gemm

  probe_dtype<<<1, 64, 0, stream>>>((const unsigned short*)hs, flag);
  cvt_hs<<<dim3(3072), 256, 0, stream>>>(hs, hsb, flag);

  // weights -> bf16 B^T rows of WT
  tr_any<<<dim3(6, 48, 1),  256, 0, stream>>>(Wq, WT,              1536, 192,  192,  0, 0, flag);
  tr_any<<<dim3(6, 48, 1),  256, 0, stream>>>(Wk, WT + 192 * 1536, 1536, 192,  192,  0, 0, flag);
  tr_any<<<dim3(48, 48, 1), 256, 0, stream>>>(Wv, WT + 384 * 1536, 1536, 1536, 1536, 0, 0, flag);

  // fused q|k|v projection: [4096][1536] @ WT^T -> qkvb [4096][1920]
  gemm_bt<<<dim3(15, 32, 1), 256, 0, stream>>>(hsb, WT, qkvb, 4096, 1920, 1536, nullptr);

  // v columns of qkvb -> per-(b,h) [hd][l]
  tr_any<<<dim3(48, 64, 2), 256, 0, stream>>>(qkvb + 384, vT, 2048, 1536, 1920,
                                              (long long)2048 * 1920, (long long)1536 * 2048,
                                              nullptr);

  // Wo -> B^T (reuses WT region; qkv gemm already consumed it)
  tr_any<<<dim3(48, 48, 1), 256, 0, stream>>>(Wo, WT, 1536, 1536, 1536, 0, 0, flag);

  // fused causal based-attention (DMA-staged V)
  attn_based<<<dim3(24, 32, 1), 256, 0, stream>>>(qkvb, vT, obuf);

  // output projection -> d_out (fp32 store if flag)
  gemm_bt<<<dim3(12, 32, 1), 256, 0, stream>>>(obuf, WT, d_out, 4096, 1536, 1536, flag);
}

// Round 9
// 243.777 us; speedup vs baseline: 2.0908x; 1.0567x over previous
//
#include <hip/hip_runtime.h>
#include <hip/hip_bf16.h>

// ---- types ------------------------------------------------------------
typedef short short8 __attribute__((ext_vector_type(8)));   // 8 bf16 MFMA A/B frag
typedef float f32x4  __attribute__((ext_vector_type(4)));   // MFMA C/D frag
typedef unsigned int u32x4 __attribute__((ext_vector_type(4))); // 16B vehicle

union V16   { u32x4 v; short8 s; };
union U16x8 { u32x4 v; unsigned short u[8]; };
union FB4   { u32x4 v; float f[4]; };
union BF2U  { __hip_bfloat162 h; unsigned int u; };

__device__ inline unsigned short f2bf(float f) {
  union { float f; unsigned int u; } x; x.f = f;
  unsigned int u = x.u + 0x7fffu + ((x.u >> 16) & 1u);   // RNE
  return (unsigned short)(u >> 16);
}

// fp32-vs-bf16 input detection from hs's first 64 even u16 words (uniform
// across the device; replaces the probe kernel — saves a dispatch).
__device__ __forceinline__ int probe_fp32(const unsigned short* hs) {
  int bad = 0;
#pragma unroll
  for (int i = 0; i < 64; ++i) {
    unsigned int e = (hs[2 * i] >> 7) & 0xFFu;
    if (e >= 0xFEu || (e > 0u && e < 0x60u)) bad++;
  }
  return bad >= 6;
}

// async global->LDS DMA, 16B/lane; LDS dest = wave-uniform base + lane*16
__device__ __forceinline__ void gl_lds16(const unsigned short* g, unsigned short* l) {
  __builtin_amdgcn_global_load_lds(
      (const __attribute__((address_space(1))) unsigned int*)g,
      (__attribute__((address_space(3))) unsigned int*)l, 16, 0, 0);
}

// ---- hs -> bf16 contiguous (one-time convert; 8 el/thread) ------------
__global__ __launch_bounds__(256) void cvt_hs(const void* __restrict__ in_,
                                              unsigned short* __restrict__ out) {
  __shared__ int sf;
  if (threadIdx.x == 0) sf = probe_fp32((const unsigned short*)in_);
  __syncthreads();
  const int f = sf;
  size_t i0 = ((size_t)blockIdx.x * 256 + threadIdx.x) * 8;
  if (f) {
    const float* in = (const float*)in_;
    FB4 a, b; a.v = *(const u32x4*)&in[i0]; b.v = *(const u32x4*)&in[i0 + 4];
    U16x8 p;
#pragma unroll
    for (int j = 0; j < 4; ++j) { p.u[j] = f2bf(a.f[j]); p.u[j + 4] = f2bf(b.f[j]); }
    *(u32x4*)&out[i0] = p.v;
  } else {
    *(u32x4*)&out[i0] = *(const u32x4*)((const unsigned short*)in_ + i0);
  }
}

// ---- all 4 weight transposes in ONE kernel, grid (48,48,4) ------------
// z=0: Wq->WT[0:192), z=1: Wk->WT[192:384), z=2: Wv->WT[384:1920), z=3: Wo->WoT
__global__ __launch_bounds__(256) void w_tr(const void* __restrict__ Wq,
                                            const void* __restrict__ Wk,
                                            const void* __restrict__ Wv,
                                            const void* __restrict__ Wo,
                                            unsigned short* __restrict__ WT,
                                            unsigned short* __restrict__ WoT,
                                            const unsigned short* __restrict__ hsprobe) {
  __shared__ unsigned short t[32][33];
  __shared__ int sf;
  const int z = blockIdx.z;
  const void* in_; unsigned short* out; int C;
  if      (z == 0) { in_ = Wq; out = WT;              C = 192;  }
  else if (z == 1) { in_ = Wk; out = WT + 192 * 1536; C = 192;  }
  else if (z == 2) { in_ = Wv; out = WT + 384 * 1536; C = 1536; }
  else             { in_ = Wo; out = WoT;             C = 1536; }
  const int c0 = blockIdx.x * 32;
  if (c0 >= C) return;                     // whole-block early exit (uniform)
  if (threadIdx.x == 0) sf = probe_fp32(hsprobe);
  __syncthreads();
  const int f = sf;
  const int tx = threadIdx.x & 31, ty = threadIdx.x >> 5;
  const int r0 = blockIdx.y * 32;          // R = 1536 rows for all four
#pragma unroll
  for (int i = 0; i < 4; ++i) {
    size_t idx = (size_t)(r0 + ty + 8 * i) * C + (c0 + tx);
    t[ty + 8 * i][tx] = f ? f2bf(((const float*)in_)[idx])
                          : ((const unsigned short*)in_)[idx];
  }
  __syncthreads();
#pragma unroll
  for (int i = 0; i < 4; ++i)
    out[(size_t)(c0 + ty + 8 * i) * 1536 + (r0 + tx)] = t[tx][ty + 8 * i];
}

// ---- v transpose: out[z][c][r] = in[z][r][c] (internal bf16) ----------
__global__ __launch_bounds__(256) void tr_v(const unsigned short* __restrict__ in_,
                                            unsigned short* __restrict__ out,
                                            int R, int C, int ldin,
                                            long long in_bstride, long long out_bstride) {
  __shared__ unsigned short t[32][33];
  const size_t ibase = (size_t)blockIdx.z * in_bstride;
  const size_t obase = (size_t)blockIdx.z * out_bstride;
  const int tx = threadIdx.x & 31, ty = threadIdx.x >> 5;
  const int r0 = blockIdx.y * 32, c0 = blockIdx.x * 32;
#pragma unroll
  for (int i = 0; i < 4; ++i)
    t[ty + 8 * i][tx] = in_[ibase + (size_t)(r0 + ty + 8 * i) * ldin + (c0 + tx)];
  __syncthreads();
#pragma unroll
  for (int i = 0; i < 4; ++i)
    out[obase + (size_t)(c0 + ty + 8 * i) * R + (r0 + tx)] = t[tx][ty + 8 * i];
}

// ---- C[M][N] = A[M][K] @ BT[N][K]^T, A/BT bf16 ------------------------
// Round-9: DOUBLE-BUFFERED global_load_lds staging (one barrier per K-step;
// DMA for tile k+1 issued at iteration top, drained one compute-phase later
// by the next barrier). Unpadded tiles + global-side XOR swizzle -> 2-way
// bank probes (free). C store fp32 iff probe_src says inputs were fp32.
__global__ __launch_bounds__(256) void gemm_bt(const unsigned short* __restrict__ A,
                                               const unsigned short* __restrict__ BT,
                                               void* __restrict__ C_,
                                               int M, int N, int K,
                                               const unsigned short* __restrict__ probe_src) {
  __shared__ unsigned short As[2][128][32];
  __shared__ unsigned short Bs[2][128][32];
  const int m0 = blockIdx.y * 128, n0 = blockIdx.x * 128;
  const int tid = threadIdx.x;
  const int lane = tid & 63, w = tid >> 6;
  const int wr = w >> 1, wc = w & 1;
  const int quad = lane >> 4, mrow = lane & 15;

  const int sr = lane >> 2;                              // staging row-in-16
  const int sc = ((lane & 3) ^ ((lane >> 3) & 3)) * 8;   // swizzled global chunk
  const int fsw = ((mrow >> 1) & 3);                     // frag-read swizzle

  const f32x4 zf = {0.f, 0.f, 0.f, 0.f};
  f32x4 acc[4][4];
#pragma unroll
  for (int mt = 0; mt < 4; ++mt)
#pragma unroll
    for (int nt = 0; nt < 4; ++nt) acc[mt][nt] = zf;

  const int nk = K >> 5;
  // prologue: stage tile 0 into buffer 0
#pragma unroll
  for (int j = 0; j < 2; ++j) {
    const int r = 32 * w + 16 * j + sr;
    gl_lds16(&A [(size_t)(m0 + r) * K + sc], &As[0][32 * w + 16 * j][0]);
    gl_lds16(&BT[(size_t)(n0 + r) * K + sc], &Bs[0][32 * w + 16 * j][0]);
  }

  for (int ks = 0; ks < nk; ++ks) {
    const int cur = ks & 1;
    __syncthreads();   // drains DMA for buf[cur]; prior reads of buf[cur^1] done
    if (ks + 1 < nk) {
      const int k1 = (ks + 1) << 5;
#pragma unroll
      for (int j = 0; j < 2; ++j) {
        const int r = 32 * w + 16 * j + sr;
        gl_lds16(&A [(size_t)(m0 + r) * K + k1 + sc], &As[cur ^ 1][32 * w + 16 * j][0]);
        gl_lds16(&BT[(size_t)(n0 + r) * K + k1 + sc], &Bs[cur ^ 1][32 * w + 16 * j][0]);
      }
    }
    short8 afr[4], bfr[4];
#pragma unroll
    for (int mt = 0; mt < 4; ++mt) {
      V16 u; u.v = *(const u32x4*)&As[cur][wr * 64 + mt * 16 + mrow][(quad ^ fsw) * 8];
      afr[mt] = u.s;
    }
#pragma unroll
    for (int nt = 0; nt < 4; ++nt) {
      V16 u; u.v = *(const u32x4*)&Bs[cur][wc * 64 + nt * 16 + mrow][(quad ^ fsw) * 8];
      bfr[nt] = u.s;
    }
#pragma unroll
    for (int mt = 0; mt < 4; ++mt)
#pragma unroll
      for (int nt = 0; nt < 4; ++nt)
        acc[mt][nt] = __builtin_amdgcn_mfma_f32_16x16x32_bf16(afr[mt], bfr[nt], acc[mt][nt], 0, 0, 0);
  }

  const int of = probe_src ? probe_fp32(probe_src) : 0;
#pragma unroll
  for (int mt = 0; mt < 4; ++mt)
#pragma unroll
    for (int nt = 0; nt < 4; ++nt)
#pragma unroll
      for (int r = 0; r < 4; ++r) {
        int grow = m0 + wr * 64 + mt * 16 + quad * 4 + r;
        int gcol = n0 + wc * 64 + nt * 16 + mrow;
        size_t idx = (size_t)grow * N + gcol;
        if (of) ((float*)C_)[idx] = acc[mt][nt][r];
        else    ((unsigned short*)C_)[idx] = f2bf(acc[mt][nt][r]);
      }
}

// ---- fused causal "based" attention — DMA-staged V, double-buffered ----
// qkv: [4096][1920] bf16 (cols 0..191 q, 192..383 k); vT: [24*128][2048]
// obuf: [4096][1536]. grid (24,32): (b*12+h, q-tile). 4 waves x 16 q-rows.
__global__ __launch_bounds__(256, 3) void attn_based(const unsigned short* __restrict__ qkv,
                                                     const unsigned short* __restrict__ vT,
                                                     unsigned short* __restrict__ obuf) {
  __shared__ unsigned short Vs[2][128][64];  // unpadded (DMA dest), 32 KB
  const int LD = 1920;
  const int bh = blockIdx.x;
  const int qt = 31 - blockIdx.y;            // long blocks dispatch first (LPT)
  const int b = bh / 12, h = bh % 12;
  const int tid = threadIdx.x;
  const int lane = tid & 63, w = tid >> 6;
  const int quad = lane >> 4, mrow = lane & 15;
  const f32x4 zf = {0.f, 0.f, 0.f, 0.f};
  const bool act = (quad < 2);

  // q B-frag (loop-invariant): B[n=q=mrow][k=feature=quad*8+j]; quads 2,3 zero
  short8 bq = {0, 0, 0, 0, 0, 0, 0, 0};
  const int q_abs = qt * 64 + w * 16 + mrow;
  if (act) {
    V16 u; u.v = *(const u32x4*)&qkv[(size_t)(b * 2048 + q_abs) * LD + h * 16 + quad * 8];
    bq = u.s;
  }

  // V staging map: load j covers rows 32w+8j+(lane>>3); swizzled global chunk
  const int vr = lane >> 3;
  const int vc = ((lane & 7) ^ (lane >> 3)) * 8;
  const unsigned short* vbase = vT + (size_t)(bh * 128) * 2048;

  const unsigned short* kptr = &qkv[(size_t)(b * 2048 + mrow) * LD + 192 + h * 16 + quad * 8];

  f32x4 oacc[8];
#pragma unroll
  for (int nt = 0; nt < 8; ++nt) oacc[nt] = zf;
  float zcol = 0.f;                          // partial z for column q = mrow

  // prologue: DMA-stage V tile 0, preload k-frags for kt=0
#pragma unroll
  for (int j = 0; j < 4; ++j)
    gl_lds16(vbase + (size_t)(32 * w + 8 * j + vr) * 2048 + vc, &Vs[0][32 * w + 8 * j][0]);
  V16 kf[4];
#pragma unroll
  for (int jt = 0; jt < 4; ++jt) {
    kf[jt].s = (short8){0, 0, 0, 0, 0, 0, 0, 0};
    if (act) kf[jt].v = *(const u32x4*)(kptr + (size_t)(jt * 16) * LD);
  }
  __syncthreads();

  for (int kt = 0; kt <= qt; ++kt) {
    const int kv0 = kt * 64;
    const int cur = kt & 1;
    if (kt < qt) {
#pragma unroll
      for (int j = 0; j < 4; ++j)
        gl_lds16(vbase + (size_t)(32 * w + 8 * j + vr) * 2048 + kv0 + 64 + vc,
                 &Vs[cur ^ 1][32 * w + 8 * j][0]);
    }

    // S^T tiles: A-frag = k rows (m=kv), B-frag = bq (n=q)
    f32x4 st[4];
#pragma unroll
    for (int jt = 0; jt < 4; ++jt)
      st[jt] = __builtin_amdgcn_mfma_f32_16x16x32_bf16(kf[jt].s, bq, zf, 0, 0, 0);

    // software-pipeline k-frags for kt+1
    kptr += (size_t)64 * LD;
    if (kt < qt) {
#pragma unroll
      for (int jt = 0; jt < 4; ++jt)
        if (act) kf[jt].v = *(const u32x4*)(kptr + (size_t)(jt * 16) * LD);
    }

    // poly + causal mask + z + packed-pair cvt: attn = 1 + 0.25*s + 0.03125*s^2
    unsigned int pk[4][2];
#pragma unroll
    for (int jt = 0; jt < 4; ++jt) {
      const int kvb = kv0 + jt * 16 + quad * 4;
#pragma unroll
      for (int r2 = 0; r2 < 2; ++r2) {
        float s0 = st[jt][2 * r2], s1 = st[jt][2 * r2 + 1];
        float a0 = fmaf(s0, fmaf(s0, 0.03125f, 0.25f), 1.0f);
        float a1 = fmaf(s1, fmaf(s1, 0.03125f, 0.25f), 1.0f);
        a0 = (kvb + 2 * r2     <= q_abs) ? a0 : 0.0f;
        a1 = (kvb + 2 * r2 + 1 <= q_abs) ? a1 : 0.0f;
        zcol += a0 + a1;
        BF2U p; p.h = __float22bfloat162_rn(make_float2(a0, a1));
        pk[jt][r2] = p.u;
      }
    }
    // wave transpose C/D -> A layout + PV MFMAs (B-frags from swizzled LDS)
#pragma unroll
    for (int c = 0; c < 2; ++c) {
      union { short8 s; int wd[4]; } ap;
#pragma unroll
      for (int t = 0; t < 4; ++t) {
        int src = (2 * (quad & 1) + (t >> 1)) * 16 + mrow;
        int v0 = __shfl((int)pk[2 * c][t & 1], src, 64);
        int v1 = __shfl((int)pk[2 * c + 1][t & 1], src, 64);
        ap.wd[t] = (quad >> 1) ? v1 : v0;
      }
#pragma unroll
      for (int nt = 0; nt < 8; ++nt) {
        V16 u;
        u.v = *(const u32x4*)&Vs[cur][nt * 16 + mrow][((c * 4 + quad) ^ (mrow & 7)) * 8];
        oacc[nt] = __builtin_amdgcn_mfma_f32_16x16x32_bf16(ap.s, u.s, oacc[nt], 0, 0, 0);
      }
    }
    __syncthreads();   // drains DMA (vmcnt) + separates buffer reuse
  }
  // z: reduce partial column sums across quads; broadcast to O rows
  zcol += __shfl_xor(zcol, 16, 64);
  zcol += __shfl_xor(zcol, 32, 64);
  float inv[4];
#pragma unroll
  for (int r = 0; r < 4; ++r)
    inv[r] = 1.0f / (__shfl(zcol, quad * 4 + r, 64) + 1e-12f);
#pragma unroll
  for (int nt = 0; nt < 8; ++nt)
#pragma unroll
    for (int r = 0; r < 4; ++r)
      obuf[(size_t)(b * 2048 + qt * 64 + w * 16 + quad * 4 + r) * 1536 +
           h * 128 + nt * 16 + mrow] = f2bf(oacc[nt][r] * inv[r]);
}

// ---- launch -----------------------------------------------------------
extern "C" void kernel_launch(void* const* d_in, const int* in_sizes, int n_in,
                              void* d_out, int out_size, void* d_ws, size_t ws_size,
                              hipStream_t stream) {
  const void* hs = d_in[0];
  const void* Wq = d_in[1];
  const void* Wk = d_in[2];
  const void* Wv = d_in[3];
  const void* Wo = d_in[4];
  const unsigned short* hsp = (const unsigned short*)hs;

  // ws (~51.5 MB): WT[1920][1536] | WoT[1536][1536] | qkvb[4096][1920]
  //                | hsb[4096][1536] | vT[24*128][2048]
  unsigned short* ws   = (unsigned short*)d_ws;
  unsigned short* WT   = ws;                        // q 0..191, k 192..383, v 384..1919
  unsigned short* WoT  = WT + 1920 * 1536;
  unsigned short* qkvb = WoT + 1536 * 1536;
  unsigned short* hsb  = qkvb + 4096 * 1920;
  unsigned short* vT   = hsb + 4096 * 1536;
  unsigned short* obuf = hsb;                       // hsb dead after qkv gemm

  // hs -> bf16 (self-probing)
  cvt_hs<<<dim3(3072), 256, 0, stream>>>(hs, hsb);

  // all four weight transposes in one dispatch
  w_tr<<<dim3(48, 48, 4), 256, 0, stream>>>(Wq, Wk, Wv, Wo, WT, WoT, hsp);

  // fused q|k|v projection: [4096][1536] @ WT^T -> qkvb [4096][1920]
  gemm_bt<<<dim3(15, 32, 1), 256, 0, stream>>>(hsb, WT, qkvb, 4096, 1920, 1536, nullptr);

  // v columns of qkvb -> per-(b,h) [hd][l]
  tr_v<<<dim3(48, 64, 2), 256, 0, stream>>>(qkvb + 384, vT, 2048, 1536, 1920,
                                            (long long)2048 * 1920, (long long)1536 * 2048);

  // fused causal based-attention (DMA-staged V)
  attn_based<<<dim3(24, 32, 1), 256, 0, stream>>>(qkvb, vT, obuf);

  // output projection -> d_out (fp32 store iff inputs were fp32)
  gemm_bt<<<dim3(12, 32, 1), 256, 0, stream>>>(obuf, WoT, d_out, 4096, 1536, 1536, hsp);
}

// Round 10
// 229.866 us; speedup vs baseline: 2.2174x; 1.0605x over previous
//
#include <hip/hip_runtime.h>
#include <hip/hip_bf16.h>

// ---- types ------------------------------------------------------------
typedef short short8 __attribute__((ext_vector_type(8)));   // 8 bf16 MFMA A/B frag
typedef float f32x4  __attribute__((ext_vector_type(4)));   // MFMA C/D frag
typedef unsigned int u32x4 __attribute__((ext_vector_type(4))); // 16B vehicle

union V16   { u32x4 v; short8 s; };
union U16x8 { u32x4 v; unsigned short u[8]; };
union FB4   { u32x4 v; float f[4]; };
union BF2U  { __hip_bfloat162 h; unsigned int u; };

__device__ inline unsigned short f2bf(float f) {
  union { float f; unsigned int u; } x; x.f = f;
  unsigned int u = x.u + 0x7fffu + ((x.u >> 16) & 1u);   // RNE
  return (unsigned short)(u >> 16);
}

// fp32-vs-bf16 input detection from hs's first 64 even u16 words
__device__ __forceinline__ int probe_fp32(const unsigned short* hs) {
  int bad = 0;
#pragma unroll
  for (int i = 0; i < 64; ++i) {
    unsigned int e = (hs[2 * i] >> 7) & 0xFFu;
    if (e >= 0xFEu || (e > 0u && e < 0x60u)) bad++;
  }
  return bad >= 6;
}

// async global->LDS DMA, 16B/lane; LDS dest = wave-uniform base + lane*16
__device__ __forceinline__ void gl_lds16(const unsigned short* g, unsigned short* l) {
  __builtin_amdgcn_global_load_lds(
      (const __attribute__((address_space(1))) unsigned int*)g,
      (__attribute__((address_space(3))) unsigned int*)l, 16, 0, 0);
}

// ---- weights transpose (z=0..3) + hs convert (z=4), one dispatch ------
// z=0: Wq->WT[0:192), z=1: Wk->WT[192:384), z=2: Wv->WT[384:1920), z=3: Wo->WoT
// z=4: hs -> hsb (bf16 contiguous), block idx = y*48+x, 2048 el/block
__global__ __launch_bounds__(256) void w_tr(const void* __restrict__ Wq,
                                            const void* __restrict__ Wk,
                                            const void* __restrict__ Wv,
                                            const void* __restrict__ Wo,
                                            const void* __restrict__ hs,
                                            unsigned short* __restrict__ WT,
                                            unsigned short* __restrict__ WoT,
                                            unsigned short* __restrict__ hsb) {
  __shared__ unsigned short t[32][33];
  __shared__ int sf;
  if (threadIdx.x == 0) sf = probe_fp32((const unsigned short*)hs);
  __syncthreads();
  const int f = sf;
  const int z = blockIdx.z;
  if (z == 4) {                            // hs convert path
    size_t i0 = ((size_t)(blockIdx.y * 48 + blockIdx.x) * 256 + threadIdx.x) * 8;
    if (f) {
      const float* in = (const float*)hs;
      FB4 a, b; a.v = *(const u32x4*)&in[i0]; b.v = *(const u32x4*)&in[i0 + 4];
      U16x8 p;
#pragma unroll
      for (int j = 0; j < 4; ++j) { p.u[j] = f2bf(a.f[j]); p.u[j + 4] = f2bf(b.f[j]); }
      *(u32x4*)&hsb[i0] = p.v;
    } else {
      *(u32x4*)&hsb[i0] = *(const u32x4*)((const unsigned short*)hs + i0);
    }
    return;
  }
  if (blockIdx.y >= 48) return;            // transpose paths: 48x48 grid
  const void* in_; unsigned short* out; int C;
  if      (z == 0) { in_ = Wq; out = WT;              C = 192;  }
  else if (z == 1) { in_ = Wk; out = WT + 192 * 1536; C = 192;  }
  else if (z == 2) { in_ = Wv; out = WT + 384 * 1536; C = 1536; }
  else             { in_ = Wo; out = WoT;             C = 1536; }
  const int c0 = blockIdx.x * 32;
  if (c0 >= C) return;                     // uniform early exit
  const int tx = threadIdx.x & 31, ty = threadIdx.x >> 5;
  const int r0 = blockIdx.y * 32;          // R = 1536 rows for all four
#pragma unroll
  for (int i = 0; i < 4; ++i) {
    size_t idx = (size_t)(r0 + ty + 8 * i) * C + (c0 + tx);
    t[ty + 8 * i][tx] = f ? f2bf(((const float*)in_)[idx])
                          : ((const unsigned short*)in_)[idx];
  }
  __syncthreads();
#pragma unroll
  for (int i = 0; i < 4; ++i)
    out[(size_t)(c0 + ty + 8 * i) * 1536 + (r0 + tx)] = t[tx][ty + 8 * i];
}

// ---- v transpose: out[z][c][r] = in[z][r][c] (internal bf16) ----------
__global__ __launch_bounds__(256) void tr_v(const unsigned short* __restrict__ in_,
                                            unsigned short* __restrict__ out,
                                            int R, int C, int ldin,
                                            long long in_bstride, long long out_bstride) {
  __shared__ unsigned short t[32][33];
  const size_t ibase = (size_t)blockIdx.z * in_bstride;
  const size_t obase = (size_t)blockIdx.z * out_bstride;
  const int tx = threadIdx.x & 31, ty = threadIdx.x >> 5;
  const int r0 = blockIdx.y * 32, c0 = blockIdx.x * 32;
#pragma unroll
  for (int i = 0; i < 4; ++i)
    t[ty + 8 * i][tx] = in_[ibase + (size_t)(r0 + ty + 8 * i) * ldin + (c0 + tx)];
  __syncthreads();
#pragma unroll
  for (int i = 0; i < 4; ++i)
    out[obase + (size_t)(c0 + ty + 8 * i) * R + (r0 + tx)] = t[tx][ty + 8 * i];
}

// ---- C[M][N] = A[M][K] @ BT[N][K]^T, A/BT bf16 ------------------------
// Round-10: BK=64 double-buffered global_load_lds (24 barriers for K=1536
// instead of 48 — the barrier drain is the cost at 1.5-2 grid-limited
// blocks/CU). Unpadded 128x64 tiles, global-side XOR swizzle
// lc=(lane&7)^(lane>>3); frag probe (kq*4+quad)^(mrow&7) -> uniform banks.
__global__ __launch_bounds__(256) void gemm_bt(const unsigned short* __restrict__ A,
                                               const unsigned short* __restrict__ BT,
                                               void* __restrict__ C_,
                                               int M, int N, int K,
                                               const unsigned short* __restrict__ probe_src) {
  __shared__ unsigned short As[2][128][64];
  __shared__ unsigned short Bs[2][128][64];
  const int m0 = blockIdx.y * 128, n0 = blockIdx.x * 128;
  const int tid = threadIdx.x;
  const int lane = tid & 63, w = tid >> 6;
  const int wr = w >> 1, wc = w & 1;
  const int quad = lane >> 4, mrow = lane & 15;

  const int sr = lane >> 3;                          // staging row-in-8
  const int sc = ((lane & 7) ^ (lane >> 3)) * 8;     // swizzled global chunk (shorts)
  const int fsw = (mrow & 7);                        // frag-read swizzle

  const f32x4 zf = {0.f, 0.f, 0.f, 0.f};
  f32x4 acc[4][4];
#pragma unroll
  for (int mt = 0; mt < 4; ++mt)
#pragma unroll
    for (int nt = 0; nt < 4; ++nt) acc[mt][nt] = zf;

  const int nk = K >> 6;                             // BK=64 steps
  // prologue: stage tile 0 into buffer 0 (4 A-loads + 4 B-loads per wave)
#pragma unroll
  for (int j = 0; j < 4; ++j) {
    const int r = 32 * w + 8 * j + sr;
    gl_lds16(&A [(size_t)(m0 + r) * K + sc], &As[0][32 * w + 8 * j][0]);
    gl_lds16(&BT[(size_t)(n0 + r) * K + sc], &Bs[0][32 * w + 8 * j][0]);
  }

  for (int ks = 0; ks < nk; ++ks) {
    const int cur = ks & 1;
    __syncthreads();   // drains DMA for buf[cur]; prior reads of buf[cur^1] done
    if (ks + 1 < nk) {
      const int k1 = (ks + 1) << 6;
#pragma unroll
      for (int j = 0; j < 4; ++j) {
        const int r = 32 * w + 8 * j + sr;
        gl_lds16(&A [(size_t)(m0 + r) * K + k1 + sc], &As[cur ^ 1][32 * w + 8 * j][0]);
        gl_lds16(&BT[(size_t)(n0 + r) * K + k1 + sc], &Bs[cur ^ 1][32 * w + 8 * j][0]);
      }
    }
#pragma unroll
    for (int kq = 0; kq < 2; ++kq) {
      short8 afr[4], bfr[4];
#pragma unroll
      for (int mt = 0; mt < 4; ++mt) {
        V16 u; u.v = *(const u32x4*)&As[cur][wr * 64 + mt * 16 + mrow][((kq * 4 + quad) ^ fsw) * 8];
        afr[mt] = u.s;
      }
#pragma unroll
      for (int nt = 0; nt < 4; ++nt) {
        V16 u; u.v = *(const u32x4*)&Bs[cur][wc * 64 + nt * 16 + mrow][((kq * 4 + quad) ^ fsw) * 8];
        bfr[nt] = u.s;
      }
#pragma unroll
      for (int mt = 0; mt < 4; ++mt)
#pragma unroll
        for (int nt = 0; nt < 4; ++nt)
          acc[mt][nt] = __builtin_amdgcn_mfma_f32_16x16x32_bf16(afr[mt], bfr[nt], acc[mt][nt], 0, 0, 0);
    }
  }

  const int of = probe_src ? probe_fp32(probe_src) : 0;
#pragma unroll
  for (int mt = 0; mt < 4; ++mt)
#pragma unroll
    for (int nt = 0; nt < 4; ++nt)
#pragma unroll
      for (int r = 0; r < 4; ++r) {
        int grow = m0 + wr * 64 + mt * 16 + quad * 4 + r;
        int gcol = n0 + wc * 64 + nt * 16 + mrow;
        size_t idx = (size_t)grow * N + gcol;
        if (of) ((float*)C_)[idx] = acc[mt][nt][r];
        else    ((unsigned short*)C_)[idx] = f2bf(acc[mt][nt][r]);
      }
}

// ---- fused causal "based" attention — DMA-staged V, double-buffered ----
// qkv: [4096][1920] bf16 (cols 0..191 q, 192..383 k); vT: [24*128][2048]
// obuf: [4096][1536]. grid (24,32): (b*12+h, q-tile). 4 waves x 16 q-rows.
__global__ __launch_bounds__(256, 3) void attn_based(const unsigned short* __restrict__ qkv,
                                                     const unsigned short* __restrict__ vT,
                                                     unsigned short* __restrict__ obuf) {
  __shared__ unsigned short Vs[2][128][64];  // unpadded (DMA dest), 32 KB
  const int LD = 1920;
  const int bh = blockIdx.x;
  const int qt = 31 - blockIdx.y;            // long blocks dispatch first (LPT)
  const int b = bh / 12, h = bh % 12;
  const int tid = threadIdx.x;
  const int lane = tid & 63, w = tid >> 6;
  const int quad = lane >> 4, mrow = lane & 15;
  const f32x4 zf = {0.f, 0.f, 0.f, 0.f};
  const bool act = (quad < 2);

  // q B-frag (loop-invariant): B[n=q=mrow][k=feature=quad*8+j]; quads 2,3 zero
  short8 bq = {0, 0, 0, 0, 0, 0, 0, 0};
  const int q_abs = qt * 64 + w * 16 + mrow;
  if (act) {
    V16 u; u.v = *(const u32x4*)&qkv[(size_t)(b * 2048 + q_abs) * LD + h * 16 + quad * 8];
    bq = u.s;
  }

  // V staging map: load j covers rows 32w+8j+(lane>>3); swizzled global chunk
  const int vr = lane >> 3;
  const int vc = ((lane & 7) ^ (lane >> 3)) * 8;
  const unsigned short* vbase = vT + (size_t)(bh * 128) * 2048;

  const unsigned short* kptr = &qkv[(size_t)(b * 2048 + mrow) * LD + 192 + h * 16 + quad * 8];

  f32x4 oacc[8];
#pragma unroll
  for (int nt = 0; nt < 8; ++nt) oacc[nt] = zf;
  float zcol = 0.f;                          // partial z for column q = mrow

  // prologue: DMA-stage V tile 0, preload k-frags for kt=0
#pragma unroll
  for (int j = 0; j < 4; ++j)
    gl_lds16(vbase + (size_t)(32 * w + 8 * j + vr) * 2048 + vc, &Vs[0][32 * w + 8 * j][0]);
  V16 kf[4];
#pragma unroll
  for (int jt = 0; jt < 4; ++jt) {
    kf[jt].s = (short8){0, 0, 0, 0, 0, 0, 0, 0};
    if (act) kf[jt].v = *(const u32x4*)(kptr + (size_t)(jt * 16) * LD);
  }
  __syncthreads();

  for (int kt = 0; kt <= qt; ++kt) {
    const int kv0 = kt * 64;
    const int cur = kt & 1;
    if (kt < qt) {
#pragma unroll
      for (int j = 0; j < 4; ++j)
        gl_lds16(vbase + (size_t)(32 * w + 8 * j + vr) * 2048 + kv0 + 64 + vc,
                 &Vs[cur ^ 1][32 * w + 8 * j][0]);
    }

    // S^T tiles: A-frag = k rows (m=kv), B-frag = bq (n=q)
    f32x4 st[4];
#pragma unroll
    for (int jt = 0; jt < 4; ++jt)
      st[jt] = __builtin_amdgcn_mfma_f32_16x16x32_bf16(kf[jt].s, bq, zf, 0, 0, 0);

    // software-pipeline k-frags for kt+1
    kptr += (size_t)64 * LD;
    if (kt < qt) {
#pragma unroll
      for (int jt = 0; jt < 4; ++jt)
        if (act) kf[jt].v = *(const u32x4*)(kptr + (size_t)(jt * 16) * LD);
    }

    // poly + causal mask + z + packed-pair cvt: attn = 1 + 0.25*s + 0.03125*s^2
    unsigned int pk[4][2];
#pragma unroll
    for (int jt = 0; jt < 4; ++jt) {
      const int kvb = kv0 + jt * 16 + quad * 4;
#pragma unroll
      for (int r2 = 0; r2 < 2; ++r2) {
        float s0 = st[jt][2 * r2], s1 = st[jt][2 * r2 + 1];
        float a0 = fmaf(s0, fmaf(s0, 0.03125f, 0.25f), 1.0f);
        float a1 = fmaf(s1, fmaf(s1, 0.03125f, 0.25f), 1.0f);
        a0 = (kvb + 2 * r2     <= q_abs) ? a0 : 0.0f;
        a1 = (kvb + 2 * r2 + 1 <= q_abs) ? a1 : 0.0f;
        zcol += a0 + a1;
        BF2U p; p.h = __float22bfloat162_rn(make_float2(a0, a1));
        pk[jt][r2] = p.u;
      }
    }
    // wave transpose C/D -> A layout + PV MFMAs (B-frags from swizzled LDS)
#pragma unroll
    for (int c = 0; c < 2; ++c) {
      union { short8 s; int wd[4]; } ap;
#pragma unroll
      for (int t = 0; t < 4; ++t) {
        int src = (2 * (quad & 1) + (t >> 1)) * 16 + mrow;
        int v0 = __shfl((int)pk[2 * c][t & 1], src, 64);
        int v1 = __shfl((int)pk[2 * c + 1][t & 1], src, 64);
        ap.wd[t] = (quad >> 1) ? v1 : v0;
      }
#pragma unroll
      for (int nt = 0; nt < 8; ++nt) {
        V16 u;
        u.v = *(const u32x4*)&Vs[cur][nt * 16 + mrow][((c * 4 + quad) ^ (mrow & 7)) * 8];
        oacc[nt] = __builtin_amdgcn_mfma_f32_16x16x32_bf16(ap.s, u.s, oacc[nt], 0, 0, 0);
      }
    }
    __syncthreads();   // drains DMA (vmcnt) + separates buffer reuse
  }
  // z: reduce partial column sums across quads; broadcast to O rows
  zcol += __shfl_xor(zcol, 16, 64);
  zcol += __shfl_xor(zcol, 32, 64);
  float inv[4];
#pragma unroll
  for (int r = 0; r < 4; ++r)
    inv[r] = 1.0f / (__shfl(zcol, quad * 4 + r, 64) + 1e-12f);
#pragma unroll
  for (int nt = 0; nt < 8; ++nt)
#pragma unroll
    for (int r = 0; r < 4; ++r)
      obuf[(size_t)(b * 2048 + qt * 64 + w * 16 + quad * 4 + r) * 1536 +
           h * 128 + nt * 16 + mrow] = f2bf(oacc[nt][r] * inv[r]);
}

// ---- launch -----------------------------------------------------------
extern "C" void kernel_launch(void* const* d_in, const int* in_sizes, int n_in,
                              void* d_out, int out_size, void* d_ws, size_t ws_size,
                              hipStream_t stream) {
  const void* hs = d_in[0];
  const void* Wq = d_in[1];
  const void* Wk = d_in[2];
  const void* Wv = d_in[3];
  const void* Wo = d_in[4];
  const unsigned short* hsp = (const unsigned short*)hs;

  // ws (~51.5 MB): WT[1920][1536] | WoT[1536][1536] | qkvb[4096][1920]
  //                | hsb[4096][1536] | vT[24*128][2048]
  unsigned short* ws   = (unsigned short*)d_ws;
  unsigned short* WT   = ws;                        // q 0..191, k 192..383, v 384..1919
  unsigned short* WoT  = WT + 1920 * 1536;
  unsigned short* qkvb = WoT + 1536 * 1536;
  unsigned short* hsb  = qkvb + 4096 * 1920;
  unsigned short* vT   = hsb + 4096 * 1536;
  unsigned short* obuf = hsb;                       // hsb dead after qkv gemm

  // weights transpose + hs convert, one dispatch
  w_tr<<<dim3(48, 64, 5), 256, 0, stream>>>(Wq, Wk, Wv, Wo, hs, WT, WoT, hsb);

  // fused q|k|v projection: [4096][1536] @ WT^T -> qkvb [4096][1920]
  gemm_bt<<<dim3(15, 32, 1), 256, 0, stream>>>(hsb, WT, qkvb, 4096, 1920, 1536, nullptr);

  // v columns of qkvb -> per-(b,h) [hd][l]
  tr_v<<<dim3(48, 64, 2), 256, 0, stream>>>(qkvb + 384, vT, 2048, 1536, 1920,
                                            (long long)2048 * 1920, (long long)1536 * 2048);

  // fused causal based-attention (DMA-staged V)
  attn_based<<<dim3(24, 32, 1), 256, 0, stream>>>(qkvb, vT, obuf);

  // output projection -> d_out (fp32 store iff inputs were fp32)
  gemm_bt<<<dim3(12, 32, 1), 256, 0, stream>>>(obuf, WoT, d_out, 4096, 1536, 1536, hsp);
}